// Round 8
// baseline (19981.456 us; speedup 1.0000x reference)
//
#include <hip/hip_runtime.h>
#include <math.h>

typedef _Float16 f16;
typedef _Float16 f16x8 __attribute__((ext_vector_type(8)));
typedef float f32x4 __attribute__((ext_vector_type(4)));
union HU { f16 h; unsigned short u; };
union AFU { unsigned long long q[2]; f16x8 v; };

#define NT 512
#define NG1 8
#define G2B 8
#define NG2 16
#define PRB 24
#define ATB 25
#define NBLK 89
#define ABE 69632           // dwords: both panel parity buffers (2 x 64 x 1088 f16)
#define ABEH 69632          // f16 elements per single parity buffer
#define OUTG_OFF 69632      // float offset in ws (2 parity buffers of 64x128)
#define LOSS_OFF 86016
#define FLAG_OFF 86144
#define DYN_LDS 136704
#define G1LW 520
#define G2LW 1032
#define PRLW 520

// ---- loads: COMPILER-VISIBLE relaxed agent-scope atomics (round-4-proven).
// The compiler models their latency and inserts correct waitcnts even when
// values are spilled/reloaded (inline-asm loads corrupted under spilling).
__device__ __forceinline__ unsigned long long ald64(const void* p) {
  return __hip_atomic_load((const unsigned long long*)p, __ATOMIC_RELAXED, __HIP_MEMORY_SCOPE_AGENT);
}
__device__ __forceinline__ unsigned ald32(const void* p) {
  return __hip_atomic_load((const unsigned*)p, __ATOMIC_RELAXED, __HIP_MEMORY_SCOPE_AGENT);
}
// ---- stores: inline asm sc0 sc1 (no output reg -> no spill hazard) ----
__device__ __forceinline__ void cst32(void* p, unsigned v) {
  asm volatile("global_store_dword %0, %1, off sc0 sc1" :: "v"(p), "v"(v) : "memory");
}
__device__ __forceinline__ void cst128h(void* p, f16x8 v) {
  asm volatile("global_store_dwordx4 %0, %1, off sc0 sc1" :: "v"(p), "v"(v) : "memory");
}
__device__ __forceinline__ void cst128f(void* p, f32x4 v) {
  asm volatile("global_store_dwordx4 %0, %1, off sc0 sc1" :: "v"(p), "v"(v) : "memory");
}
#define VMWAIT() do { asm volatile("s_waitcnt vmcnt(0)" ::: "memory"); \
                      __builtin_amdgcn_sched_barrier(0); } while (0)

__device__ __forceinline__ float sigm(float v){ return 1.f/(1.f+expf(-v)); }

// ---- flag barrier: store own slot (after draining asm stores), poll via
// compiler-visible atomic loads. 96 dword slots = 48 qwords, lanes 0..47.
__device__ __forceinline__ void gbar(unsigned* flags, unsigned target) {
  VMWAIT();
  __syncthreads();
  if (threadIdx.x == 0) cst32(flags + blockIdx.x, target);
  if (threadIdx.x < 64) {
    bool ok;
    do {
      unsigned lo = target, hi = target;
      if (threadIdx.x < 48) {
        unsigned long long v = ald64(flags + threadIdx.x * 2);
        lo = (unsigned)v; hi = (unsigned)(v >> 32);
      }
      ok = (lo >= target) && (hi >= target);
    } while (!__all(ok));
  }
  __syncthreads();
}

__device__ __forceinline__ float mix_loss(const float* so, const float* yl, int t, int m) {
  float y1 = yl[t*3+0], y2 = yl[t*3+1], ys = yl[t*3+2];
  float ph = (m < 20) ? so[1+m] : -1e30f;
  float mx = ph;
  #pragma unroll
  for (int d = 16; d >= 1; d >>= 1) mx = fmaxf(mx, __shfl_xor(mx, d));
  float pe = (m < 20) ? expf(ph - mx) : 0.f;
  float ps = pe;
  #pragma unroll
  for (int d = 16; d >= 1; d >>= 1) ps += __shfl_xor(ps, d);
  float contrib = 0.f;
  if (m < 20) {
    float mu1 = so[21+m], mu2 = so[41+m];
    float s1 = expf(so[61+m]), s2 = expf(so[81+m]);
    float rh = tanhf(so[101+m]);
    float d1 = (y1-mu1)/s1, d2 = (y2-mu2)/s2;
    float omr = 1.f - rh*rh;
    float z = d1*d1 + d2*d2 - 2.f*rh*d1*d2;
    float ga = expf(-z/(2.f*omr)) / (6.283185307179586f * s1 * s2 * sqrtf(omr));
    contrib = (pe/ps)*ga;
  }
  float gs = contrib;
  #pragma unroll
  for (int d = 16; d >= 1; d >>= 1) gs += __shfl_xor(gs, d);
  float lg = -logf(gs + 1e-20f);
  float e = 1.f/(1.f + expf(so[0]));
  float lb = -logf((e + 1e-20f)*ys + (1.f - e + 1e-20f)*(1.f - ys));
  return lg + lb;
}

__global__ __launch_bounds__(256) void k_init(float* ws) {
  unsigned* w0 = (unsigned*)ws;
  unsigned* fl = (unsigned*)ws + FLAG_OFF;
  int idx = blockIdx.x*256 + threadIdx.x;
  int str = gridDim.x*256;
  for (int e = idx; e < ABE; e += str) w0[e] = 0u;                    // panels
  for (int e = idx; e < 2*8192 + 64; e += str) w0[OUTG_OFF + e] = 0u; // outg+lossg
  if (idx < 96) fl[idx] = (idx < NBLK) ? 0u : 0x7fffffffu;
}

__global__ __launch_bounds__(NT, 1) void kmain(
    const float* __restrict__ x, const float* __restrict__ y, const float* __restrict__ cvec,
    const float* __restrict__ Wih1, const float* __restrict__ Whh1,
    const float* __restrict__ bih1, const float* __restrict__ bhh1,
    const float* __restrict__ Wih2, const float* __restrict__ Whh2,
    const float* __restrict__ bih2, const float* __restrict__ bhh2,
    const float* __restrict__ Wk, const float* __restrict__ bk,
    const float* __restrict__ Wo, const float* __restrict__ bo,
    float* __restrict__ out, float* __restrict__ ws)
{
  extern __shared__ char dsm[];
  const int blk = blockIdx.x, tid = threadIdx.x;
  const int wv = tid >> 6, l = tid & 63;
  const int q = l & 3;

  f16* AB = (f16*)ws;
  float* outg  = ws + OUTG_OFF;        // [2 parity][64][128]
  float* lossg = ws + LOSS_OFF;
  unsigned* flags = (unsigned*)ws + FLAG_OFF;

  // union'd register state across roles
  f16x8 Bf[36];
  f32x4 acc[8];
  float cst[32];
  float bi[2] = {0.f, 0.f};
  float bpr = 0.f, lreg = 0.f;
  #pragma unroll
  for (int z = 0; z < 32; ++z) cst[z] = 0.f;

  // ---------------- role init ----------------
  if (blk < NG1) {                                  // gates1: dims blk*64..+64
    auto wg1 = [&](int R, int k)->float {
      if (k < 3) return Wih1[R*57 + k];
      if (k >= 4 && k < 58) return Wih1[R*57 + 3 + (k-4)];
      if (k >= 64 && k < 576) return Whh1[R*512 + (k-64)];
      return 0.f;
    };
    #pragma unroll
    for (int nt = 0; nt < 2; ++nt) {
      int T = wv*2 + nt;
      int n = T*16 + (l & 15);
      int R = (n & 3)*512 + blk*64 + (n >> 2);
      #pragma unroll
      for (int j = 0; j < 18; ++j) {
        f16x8 v;
        #pragma unroll
        for (int e = 0; e < 8; ++e) v[e] = (f16)wg1(R, j*32 + (l >> 4)*8 + e);
        Bf[nt*18 + j] = v;
      }
      bi[nt] = bih1[R] + bhh1[R];
    }
    unsigned* z = (unsigned*)dsm;
    for (int e = tid; e < 64*G1LW/2; e += NT) z[e] = 0u;
  } else if (blk < G2B + NG2) {                     // gates2: dims (blk-8)*32..+32
    const int g2i = blk - G2B;
    auto wg2 = [&](int R, int k)->float {
      if (k >= 4 && k < 58) return Wih2[R*569 + 515 + (k-4)];
      if (k >= 58 && k < 61) return Wih2[R*569 + (k-58)];
      if (k >= 64 && k < 576) return Wih2[R*569 + 3 + (k-64)];
      if (k >= 576) return Whh2[R*512 + (k-576)];
      return 0.f;
    };
    int n = wv*16 + (l & 15);
    int R = (n & 3)*512 + g2i*32 + (n >> 2);
    #pragma unroll
    for (int j = 0; j < 34; ++j) {
      f16x8 v;
      #pragma unroll
      for (int e = 0; e < 8; ++e) v[e] = (f16)wg2(R, j*32 + (l >> 4)*8 + e);
      Bf[j] = v;
    }
    bi[0] = bih2[R] + bhh2[R];
    unsigned* z = (unsigned*)dsm;
    for (int e = tid; e < 64*G2LW/2; e += NT) z[e] = 0u;
  } else if (blk == PRB) {                          // projection
    int o = wv*16 + (l & 15);
    #pragma unroll
    for (int j = 0; j < 16; ++j) {
      f16x8 v;
      #pragma unroll
      for (int e = 0; e < 8; ++e)
        v[e] = (o < 121) ? (f16)Wo[o*512 + j*32 + (l >> 4)*8 + e] : (f16)0.f;
      Bf[j] = v;
    }
    bpr = (o < 121) ? bo[o] : 0.f;
    unsigned* z = (unsigned*)dsm;
    for (int e = tid; e < 64*PRLW/2; e += NT) z[e] = 0u;
  } else {                                          // attention+loss: batch b
    const int b = blk - ATB;
    f16*   wk  = (f16*)dsm;                         // [30][520]
    float* cv  = (float*)(dsm + 31200);
    float* xl  = (float*)(dsm + 45024);
    float* yl  = (float*)(dsm + 52224);
    for (int e = tid; e < 30*512; e += NT) { int j = e >> 9, k = e & 511; wk[j*520 + k] = (f16)Wk[e]; }
    for (int e = tid; e < 3456; e += NT) cv[e] = cvec[b*3456 + e];
    for (int e = tid; e < 1800; e += NT) { xl[e] = x[b*1800+e]; yl[e] = y[b*1800+e]; }
    float* kap = (float*)(dsm + 61152);
    if (tid < 10) kap[tid] = 0.f;
    __syncthreads();
    if (tid == 0) {   // stage xA(0) into parity-0
      HU h0, h1u, h2u;
      h0.h = (f16)xl[0]; h1u.h = (f16)xl[1]; h2u.h = (f16)xl[2];
      cst32((unsigned*)AB + (b*1088 >> 1),       (unsigned)h0.u | ((unsigned)h1u.u << 16));
      cst32((unsigned*)AB + ((b*1088 + 2) >> 1), (unsigned)h2u.u);
    }
  }

  // biases for gates were folded above; cell states zeroed.
  gbar(flags, 1);

  // ---------------- main recurrence ----------------
  for (int i = 0; i <= 601; ++i) {
    const f16* __restrict__ Acur = AB + (i & 1)*ABEH;
    f16* __restrict__ Anxt = AB + ((i & 1)^1)*ABEH;
    unsigned* AnxtW = (unsigned*)Anxt;

    // ============ Phase A: LSTM gates (panel h-cols already in LDS) ============
    if (blk < NG1) {
      if (i <= 599) {                               // gates1 -> h1(i)
        f16* plds = (f16*)dsm;
        f16* htr  = (f16*)(dsm + 66560);
        #pragma unroll
        for (int z = 0; z < 8; ++z) acc[z] = (f32x4){0,0,0,0};
        const int kb = (l >> 4)*8;
        AFU a01[4][2];
        #pragma unroll
        for (int mt = 0; mt < 4; ++mt)
          #pragma unroll
          for (int jd = 0; jd < 2; ++jd) {
            const f16* bp = Acur + ((l&15) + 16*mt)*1088 + jd*32 + kb;
            a01[mt][jd].q[0] = ald64(bp);
            a01[mt][jd].q[1] = ald64(bp + 4);
          }
        // LDS K-portion first: global latency of a01 hides underneath
        #pragma unroll
        for (int j = 2; j < 18; ++j)
          #pragma unroll
          for (int mt = 0; mt < 4; ++mt) {
            f16x8 af = *(const f16x8*)&plds[((l&15) + 16*mt)*G1LW + (j*32 - 64) + kb];
            #pragma unroll
            for (int nt = 0; nt < 2; ++nt)
              acc[nt*4+mt] = __builtin_amdgcn_mfma_f32_16x16x32_f16(af, Bf[nt*18+j], acc[nt*4+mt], 0,0,0);
          }
        #pragma unroll
        for (int mt = 0; mt < 4; ++mt)
          #pragma unroll
          for (int jd = 0; jd < 2; ++jd)
            #pragma unroll
            for (int nt = 0; nt < 2; ++nt)
              acc[nt*4+mt] = __builtin_amdgcn_mfma_f32_16x16x32_f16(a01[mt][jd].v, Bf[nt*18+jd], acc[nt*4+mt], 0,0,0);
        #pragma unroll
        for (int nt = 0; nt < 2; ++nt) {
          int dloc = (wv*2 + nt)*4 + ((l & 15) >> 2);
          #pragma unroll
          for (int mt = 0; mt < 4; ++mt)
            #pragma unroll
            for (int r = 0; r < 4; ++r) {
              float xme = acc[nt*4+mt][r] + bi[nt];
              float a1 = __shfl_xor(xme, 1), a2 = __shfl_xor(xme, 2), a3 = __shfl_xor(a1, 2);
              float gi = q==0?xme: q==1?a1 : q==2?a2 : a3;
              float gf = q==0?a1 : q==1?xme: q==2?a3 : a2;
              float gg = q==0?a2 : q==1?a3 : q==2?xme: a1;
              float go = q==0?a3 : q==1?a2 : q==2?a1 : xme;
              float c = cst[(nt*4+mt)*4 + r];
              c = sigm(gf)*c + sigm(gi)*tanhf(gg);
              cst[(nt*4+mt)*4 + r] = c;
              float h = sigm(go)*tanhf(c);
              if (q == 0) htr[(mt*16 + (l>>4)*4 + r)*64 + dloc] = (f16)h;
            }
        }
        __syncthreads();
        { int m = tid >> 3, qq = tid & 7;
          f16x8 hv = *(const f16x8*)&htr[m*64 + qq*8];
          cst128h(Anxt + m*1088 + 64 + blk*64 + qq*8, hv); }
      }
    } else if (blk < G2B + NG2) {
      if (i >= 1 && i <= 600) {                     // gates2 -> h2(i-1)
        const int g2i = blk - G2B;
        f16* plds = (f16*)dsm;
        f16* htr  = (f16*)(dsm + 132096);
        #pragma unroll
        for (int z = 0; z < 4; ++z) acc[z] = (f32x4){0,0,0,0};
        const int kb = (l >> 4)*8;
        AFU a01[4][2];
        #pragma unroll
        for (int mt = 0; mt < 4; ++mt)
          #pragma unroll
          for (int jd = 0; jd < 2; ++jd) {
            const f16* bp = Acur + ((l&15) + 16*mt)*1088 + jd*32 + kb;
            a01[mt][jd].q[0] = ald64(bp);
            a01[mt][jd].q[1] = ald64(bp + 4);
          }
        #pragma unroll
        for (int j = 2; j < 34; ++j)
          #pragma unroll
          for (int mt = 0; mt < 4; ++mt) {
            f16x8 af = *(const f16x8*)&plds[((l&15) + 16*mt)*G2LW + (j*32 - 64) + kb];
            acc[mt] = __builtin_amdgcn_mfma_f32_16x16x32_f16(af, Bf[j], acc[mt], 0,0,0);
          }
        #pragma unroll
        for (int mt = 0; mt < 4; ++mt)
          #pragma unroll
          for (int jd = 0; jd < 2; ++jd)
            acc[mt] = __builtin_amdgcn_mfma_f32_16x16x32_f16(a01[mt][jd].v, Bf[jd], acc[mt], 0,0,0);
        {
          int dloc = wv*4 + ((l & 15) >> 2);
          #pragma unroll
          for (int mt = 0; mt < 4; ++mt)
            #pragma unroll
            for (int r = 0; r < 4; ++r) {
              float xme = acc[mt][r] + bi[0];
              float a1 = __shfl_xor(xme, 1), a2 = __shfl_xor(xme, 2), a3 = __shfl_xor(a1, 2);
              float gi = q==0?xme: q==1?a1 : q==2?a2 : a3;
              float gf = q==0?a1 : q==1?xme: q==2?a3 : a2;
              float gg = q==0?a2 : q==1?a3 : q==2?xme: a1;
              float go = q==0?a3 : q==1?a2 : q==2?a1 : xme;
              float c = cst[mt*4 + r];
              c = sigm(gf)*c + sigm(gi)*tanhf(gg);
              cst[mt*4 + r] = c;
              float h = sigm(go)*tanhf(c);
              if (q == 0) htr[(mt*16 + (l>>4)*4 + r)*32 + dloc] = (f16)h;
            }
        }
        __syncthreads();
        if (tid < 256) {
          int m = tid >> 2, qq = tid & 3;
          f16x8 hv = *(const f16x8*)&htr[m*32 + qq*8];
          cst128h(Anxt + m*1088 + 576 + g2i*32 + qq*8, hv);
        }
      }
    }
    gbar(flags, 2 + 2*i);

    // ============ Phase B: attention + proj + loss + panel ingest ============
    if (blk < NG1) {
      if (i <= 599) {                               // ingest h1 cols for next iter
        f16* plds = (f16*)dsm;
        AFU tb[8];
        #pragma unroll
        for (int it = 0; it < 8; ++it) {
          int flat = tid + it*512;
          const f16* bp = Anxt + (flat >> 6)*1088 + 64 + (flat & 63)*8;
          tb[it].q[0] = ald64(bp);
          tb[it].q[1] = ald64(bp + 4);
        }
        #pragma unroll
        for (int it = 0; it < 8; ++it) {
          int flat = tid + it*512;
          *(f16x8*)&plds[(flat >> 6)*G1LW + (flat & 63)*8] = tb[it].v;
        }
      }
    } else if (blk < G2B + NG2) {
      if (i <= 599) {                               // ingest h1+h2 cols
        f16* plds = (f16*)dsm;
        AFU tb[8];
        #pragma unroll
        for (int half = 0; half < 2; ++half) {
          #pragma unroll
          for (int it = 0; it < 8; ++it) {
            int flat = tid + (half*8 + it)*512;
            const f16* bp = Anxt + (flat >> 7)*1088 + 64 + (flat & 127)*8;
            tb[it].q[0] = ald64(bp);
            tb[it].q[1] = ald64(bp + 4);
          }
          #pragma unroll
          for (int it = 0; it < 8; ++it) {
            int flat = tid + (half*8 + it)*512;
            *(f16x8*)&plds[(flat >> 7)*G2LW + (flat & 127)*8] = tb[it].v;
          }
        }
      }
    } else if (blk == PRB) {
      if (i >= 1 && i <= 600) {                     // proj: h2(i-1) -> outg parity (i+1)&1
        f16* plds = (f16*)dsm;
        float* otr = (float*)(dsm + 66560);         // [64][128] f32
        float* outp = outg + ((i + 1) & 1)*8192;
        AFU tb[8];
        #pragma unroll
        for (int it = 0; it < 8; ++it) {
          int flat = tid + it*512;
          const f16* bp = Anxt + (flat >> 6)*1088 + 576 + (flat & 63)*8;
          tb[it].q[0] = ald64(bp);
          tb[it].q[1] = ald64(bp + 4);
        }
        #pragma unroll
        for (int it = 0; it < 8; ++it) {
          int flat = tid + it*512;
          *(f16x8*)&plds[(flat >> 6)*PRLW + (flat & 63)*8] = tb[it].v;
        }
        __syncthreads();
        #pragma unroll
        for (int z = 0; z < 4; ++z) acc[z] = (f32x4){0,0,0,0};
        const int kb = (l >> 4)*8;
        #pragma unroll
        for (int j = 0; j < 16; ++j)
          #pragma unroll
          for (int mt = 0; mt < 4; ++mt) {
            f16x8 af = *(const f16x8*)&plds[((l&15) + 16*mt)*PRLW + j*32 + kb];
            acc[mt] = __builtin_amdgcn_mfma_f32_16x16x32_f16(af, Bf[j], acc[mt], 0,0,0);
          }
        { int o = wv*16 + (l & 15);
          #pragma unroll
          for (int mt = 0; mt < 4; ++mt)
            #pragma unroll
            for (int r = 0; r < 4; ++r)
              otr[(mt*16 + (l>>4)*4 + r)*128 + o] = acc[mt][r] + bpr;
        }
        __syncthreads();
        #pragma unroll
        for (int it = 0; it < 4; ++it) {
          int flat = tid + it*512;
          int m = flat >> 5, o4 = flat & 31;
          f32x4 v4 = *(const f32x4*)&otr[m*128 + o4*4];
          cst128f(outp + m*128 + o4*4, v4);
        }
      }
    } else {
      const int b = blk - ATB;
      f16*   wk   = (f16*)dsm;
      float* cv   = (float*)(dsm + 31200);
      float* xl   = (float*)(dsm + 45024);
      float* yl   = (float*)(dsm + 52224);
      f16*   h1h  = (f16*)(dsm + 59424);
      float* so   = (float*)(dsm + 60448);
      float* skg  = (float*)(dsm + 60944);
      float* sal  = (float*)(dsm + 61072);
      float* sbe  = (float*)(dsm + 61112);
      float* kap  = (float*)(dsm + 61152);
      float* sphi = (float*)(dsm + 61192);
      float* wtmp = (float*)(dsm + 61448);
      if (i <= 599) {                               // attention(i): h1(i) -> w(i)
        if (tid < 64) {
          AFU hv;
          const f16* bp = Anxt + b*1088 + 64 + tid*8;
          hv.q[0] = ald64(bp);
          hv.q[1] = ald64(bp + 4);
          *(f16x8*)&h1h[tid*8] = hv.v;
        }
        __syncthreads();
        {
          int j = tid >> 4, ksv = tid & 15;
          float a = 0.f;
          if (j < 30) {
            const f16* wr = &wk[j*520 + ksv*32];
            const f16* hr = &h1h[ksv*32];
            #pragma unroll
            for (int c = 0; c < 4; ++c) {
              f16x8 qv = *(const f16x8*)(wr + c*8);
              f16x8 hv = *(const f16x8*)(hr + c*8);
              #pragma unroll
              for (int e = 0; e < 8; ++e) a += (float)qv[e] * (float)hv[e];
            }
          }
          a += __shfl_xor(a, 1); a += __shfl_xor(a, 2);
          a += __shfl_xor(a, 4); a += __shfl_xor(a, 8);
          if (j < 30 && ksv == 0) skg[j] = a + bk[j];
        }
        __syncthreads();
        if (tid < 10) {
          sal[tid] = expf(skg[tid]);
          sbe[tid] = expf(skg[10+tid]);
          kap[tid] += expf(skg[20+tid]);
        }
        __syncthreads();
        if (tid < 64) {
          float u = (float)tid, ph = 0.f;
          #pragma unroll
          for (int k2 = 0; k2 < 10; ++k2) {
            float d = kap[k2] - u;
            ph += sal[k2]*expf(-sbe[k2]*d*d);
          }
          sphi[tid] = ph;
        }
        __syncthreads();
        if (tid < 54) {
          float wvv = 0.f;
          #pragma unroll 8
          for (int u = 0; u < 64; ++u) wvv += sphi[u]*cv[u*54 + tid];
          wtmp[tid] = wvv;
        }
        __syncthreads();
        if (tid < 27) {
          HU a, bu; a.h = (f16)wtmp[2*tid]; bu.h = (f16)wtmp[2*tid+1];
          cst32(AnxtW + ((b*1088 + 4 + 2*tid) >> 1), (unsigned)a.u | ((unsigned)bu.u << 16));
        } else if (tid == 27) {
          HU a, bu; a.h = (f16)xl[i*3+0]; bu.h = (f16)xl[i*3+1];
          cst32(AnxtW + ((b*1088 + 58) >> 1), (unsigned)a.u | ((unsigned)bu.u << 16));
        } else if (tid == 28) {
          HU a; a.h = (f16)xl[i*3+2];
          cst32(AnxtW + ((b*1088 + 60) >> 1), (unsigned)a.u);
        } else if (tid == 29 && i <= 598) {
          HU a, bu; a.h = (f16)xl[(i+1)*3+0]; bu.h = (f16)xl[(i+1)*3+1];
          cst32(AnxtW + ((b*1088) >> 1), (unsigned)a.u | ((unsigned)bu.u << 16));
        } else if (tid == 30 && i <= 598) {
          HU a; a.h = (f16)xl[(i+1)*3+2];
          cst32(AnxtW + ((b*1088 + 2) >> 1), (unsigned)a.u);
        }
      }
      if (i >= 2) {                                 // loss(i-2) from outg parity i&1
        if (tid < 121) {
          unsigned uu = ald32((unsigned*)(outg + (i & 1)*8192) + b*128 + tid);
          float v; __builtin_memcpy(&v, &uu, 4);
          so[tid] = v;
        }
        __syncthreads();
        if (tid < 32) {
          float v = mix_loss(so, yl, i-2, tid);
          if (tid == 0) lreg += v;
        }
      }
    }
    gbar(flags, 3 + 2*i);
  }

  if (blk >= ATB && tid == 0) {
    unsigned uu; __builtin_memcpy(&uu, &lreg, 4);
    cst32((unsigned*)lossg + (blk - ATB), uu);
  }
  gbar(flags, 1206);
  if (blk == ATB && tid < 64) {
    unsigned uu = ald32((unsigned*)lossg + tid);
    float v; __builtin_memcpy(&v, &uu, 4);
    #pragma unroll
    for (int d = 32; d >= 1; d >>= 1) v += __shfl_xor(v, d);
    if (tid == 0) out[0] = v / 38400.f;
  }
}

extern "C" void kernel_launch(void* const* d_in, const int* in_sizes, int n_in,
                              void* d_out, int out_size, void* d_ws, size_t ws_size,
                              hipStream_t stream)
{
  (void)in_sizes; (void)n_in; (void)out_size; (void)ws_size;
  const float* x    = (const float*)d_in[0];
  const float* y    = (const float*)d_in[1];
  const float* cvec = (const float*)d_in[2];
  const float* Wih1 = (const float*)d_in[3];
  const float* Whh1 = (const float*)d_in[4];
  const float* bih1 = (const float*)d_in[5];
  const float* bhh1 = (const float*)d_in[6];
  const float* Wih2 = (const float*)d_in[7];
  const float* Whh2 = (const float*)d_in[8];
  const float* bih2 = (const float*)d_in[9];
  const float* bhh2 = (const float*)d_in[10];
  const float* Wk   = (const float*)d_in[11];
  const float* bk   = (const float*)d_in[12];
  const float* Wo   = (const float*)d_in[13];
  const float* bo   = (const float*)d_in[14];
  float* out = (float*)d_out;
  float* wsf = (float*)d_ws;

  hipFuncSetAttribute((const void*)kmain, hipFuncAttributeMaxDynamicSharedMemorySize, DYN_LDS);

  k_init<<<256, 256, 0, stream>>>(wsf);

  void* args[] = {
    (void*)&x, (void*)&y, (void*)&cvec,
    (void*)&Wih1, (void*)&Whh1, (void*)&bih1, (void*)&bhh1,
    (void*)&Wih2, (void*)&Whh2, (void*)&bih2, (void*)&bhh2,
    (void*)&Wk, (void*)&bk, (void*)&Wo, (void*)&bo,
    (void*)&out, (void*)&wsf
  };
  hipLaunchCooperativeKernel((void*)kmain, dim3(NBLK), dim3(NT), args, DYN_LDS, stream);
}

// Round 10
// 15478.008 us; speedup vs baseline: 1.2910x; 1.2910x over previous
//
#include <hip/hip_runtime.h>
#include <math.h>

typedef _Float16 f16;
typedef _Float16 f16x8 __attribute__((ext_vector_type(8)));
typedef float f32x4 __attribute__((ext_vector_type(4)));
union HU { f16 h; unsigned short u; };

#define NT 512
#define NG1 16              // blocks 0..15: gates1, 32 dims each
#define G2B 16
#define NG2 16              // blocks 16..31: gates2, 32 dims each
#define PRB 32
#define ATB 33
#define NBLK 97
#define ABE 69632           // dwords: both panel parity buffers (2 x 64 x 1088 f16)
#define ABEH 69632          // f16 elements per single parity buffer
#define OUTG_OFF 69632      // float offset (2 parity buffers of 64x128)
#define LOSS_OFF 86016
#define FLAG_OFF 86144
// prepacked fragment-linear weights (f16), float offsets:
#define W2OFF_F 86400       // 16 blocks x 139264 f16 (gates2)
#define W1OFF_F 1200512     // 16 blocks x 73728 f16 (gates1)
#define WPOFF_F 1790336     // 65536 f16 (proj)
#define G2PER 139264
#define G1PER 73728
#define DYN_LDS 136704
#define G1LW 520
#define G2LW 1032
#define PRLW 520

// ---- coherent (cross-XCD) loads: inline asm sc0 sc1. SAFE at low register
// pressure only (no spills) — this kernel keeps every path ~<=130 VGPR.
__device__ __forceinline__ f16x8 cld16(const void* p) {
  f16x8 r;
  asm volatile("global_load_dwordx4 %0, %1, off sc0 sc1" : "=v"(r) : "v"(p) : "memory");
  return r;
}
// low-rate loads: compiler-visible atomics (correct even if spilled)
__device__ __forceinline__ unsigned long long ald64(const void* p) {
  return __hip_atomic_load((const unsigned long long*)p, __ATOMIC_RELAXED, __HIP_MEMORY_SCOPE_AGENT);
}
__device__ __forceinline__ unsigned ald32(const void* p) {
  return __hip_atomic_load((const unsigned*)p, __ATOMIC_RELAXED, __HIP_MEMORY_SCOPE_AGENT);
}
// stores: asm (no output reg -> no spill hazard)
__device__ __forceinline__ void cst32(void* p, unsigned v) {
  asm volatile("global_store_dword %0, %1, off sc0 sc1" :: "v"(p), "v"(v) : "memory");
}
__device__ __forceinline__ void cst128h(void* p, f16x8 v) {
  asm volatile("global_store_dwordx4 %0, %1, off sc0 sc1" :: "v"(p), "v"(v) : "memory");
}
__device__ __forceinline__ void cst128f(void* p, f32x4 v) {
  asm volatile("global_store_dwordx4 %0, %1, off sc0 sc1" :: "v"(p), "v"(v) : "memory");
}
#define VMWAIT() do { asm volatile("s_waitcnt vmcnt(0)" ::: "memory"); \
                      __builtin_amdgcn_sched_barrier(0); } while (0)

__device__ __forceinline__ float sigm(float v){ return 1.f/(1.f+expf(-v)); }

// flag barrier: 97 blocks, monotonic targets; poll via atomic qword loads
__device__ __forceinline__ void gbar(unsigned* flags, unsigned target) {
  VMWAIT();
  __syncthreads();
  if (threadIdx.x == 0) cst32(flags + blockIdx.x, target);
  if (threadIdx.x < 64) {
    bool ok;
    do {
      unsigned lo = target, hi = target;
      if (threadIdx.x < 49) {
        unsigned long long v = ald64(flags + threadIdx.x * 2);
        lo = (unsigned)v; hi = (unsigned)(v >> 32);
      }
      ok = (lo >= target) && (hi >= target);
    } while (!__all(ok));
  }
  __syncthreads();
}

__device__ __forceinline__ float mix_loss(const float* so, const float* yl, int t, int m) {
  float y1 = yl[t*3+0], y2 = yl[t*3+1], ys = yl[t*3+2];
  float ph = (m < 20) ? so[1+m] : -1e30f;
  float mx = ph;
  #pragma unroll
  for (int d = 16; d >= 1; d >>= 1) mx = fmaxf(mx, __shfl_xor(mx, d));
  float pe = (m < 20) ? expf(ph - mx) : 0.f;
  float ps = pe;
  #pragma unroll
  for (int d = 16; d >= 1; d >>= 1) ps += __shfl_xor(ps, d);
  float contrib = 0.f;
  if (m < 20) {
    float mu1 = so[21+m], mu2 = so[41+m];
    float s1 = expf(so[61+m]), s2 = expf(so[81+m]);
    float rh = tanhf(so[101+m]);
    float d1 = (y1-mu1)/s1, d2 = (y2-mu2)/s2;
    float omr = 1.f - rh*rh;
    float z = d1*d1 + d2*d2 - 2.f*rh*d1*d2;
    float ga = expf(-z/(2.f*omr)) / (6.283185307179586f * s1 * s2 * sqrtf(omr));
    contrib = (pe/ps)*ga;
  }
  float gs = contrib;
  #pragma unroll
  for (int d = 16; d >= 1; d >>= 1) gs += __shfl_xor(gs, d);
  float lg = -logf(gs + 1e-20f);
  float e = 1.f/(1.f + expf(so[0]));
  float lb = -logf((e + 1e-20f)*ys + (1.f - e + 1e-20f)*(1.f - ys));
  return lg + lb;
}

__global__ __launch_bounds__(256) void k_init(float* ws,
    const float* __restrict__ Wih1, const float* __restrict__ Whh1,
    const float* __restrict__ Wih2, const float* __restrict__ Whh2,
    const float* __restrict__ Wo)
{
  unsigned* w0 = (unsigned*)ws;
  unsigned* fl = (unsigned*)ws + FLAG_OFF;
  int idx = blockIdx.x*256 + threadIdx.x;
  int str = gridDim.x*256;
  for (int e = idx; e < ABE; e += str) w0[e] = 0u;                    // panels
  for (int e = idx; e < 2*8192 + 64; e += str) w0[OUTG_OFF + e] = 0u; // outg+lossg
  if (idx < 128) fl[idx] = (idx < NBLK) ? 0u : 0x7fffffffu;

  // ---- prepack weights into MFMA-fragment-linear order ----
  f16* w2p = (f16*)(ws + W2OFF_F);
  f16* w1p = (f16*)(ws + W1OFF_F);
  f16* wpp = (f16*)(ws + WPOFF_F);
  const int G2T = 16*G2PER, G1T = 16*G1PER, PPT = 65536;
  for (int e = idx; e < G2T; e += str) {
    int bi = e / G2PER, r0 = e - bi*G2PER;
    int sub = r0 & 7, frag = r0 >> 3;
    int l = frag & 63, t = frag >> 6;
    int nt = t & 7, j = t >> 3;               // j in [0,34)
    int n = nt*16 + (l & 15);
    int R = (n & 3)*512 + bi*32 + (n >> 2);
    int k = j*32 + ((l >> 4) << 3) + sub;
    float v = 0.f;
    if (k >= 4 && k < 58)        v = Wih2[R*569 + 515 + (k-4)];
    else if (k >= 58 && k < 61)  v = Wih2[R*569 + (k-58)];
    else if (k >= 64 && k < 576) v = Wih2[R*569 + 3 + (k-64)];
    else if (k >= 576)           v = Whh2[R*512 + (k-576)];
    w2p[e] = (f16)v;
  }
  for (int e = idx; e < G1T; e += str) {
    int bi = e / G1PER, r0 = e - bi*G1PER;
    int sub = r0 & 7, frag = r0 >> 3;
    int l = frag & 63, t = frag >> 6;
    int nt = t & 7, j = t >> 3;               // j in [0,18)
    int n = nt*16 + (l & 15);
    int R = (n & 3)*512 + bi*32 + (n >> 2);
    int k = j*32 + ((l >> 4) << 3) + sub;
    float v = 0.f;
    if (k < 3)                   v = Wih1[R*57 + k];
    else if (k >= 4 && k < 58)   v = Wih1[R*57 + 3 + (k-4)];
    else if (k >= 64 && k < 576) v = Whh1[R*512 + (k-64)];
    w1p[e] = (f16)v;
  }
  for (int e = idx; e < PPT; e += str) {
    int sub = e & 7, frag = e >> 3;
    int l = frag & 63, t = frag >> 6;
    int nt = t & 7, j = t >> 3;               // j in [0,16)
    int o = nt*16 + (l & 15);
    int k = j*32 + ((l >> 4) << 3) + sub;
    wpp[e] = (o < 121) ? (f16)Wo[o*512 + k] : (f16)0.f;
  }
}

__global__ __launch_bounds__(NT, 1) void kmain(
    const float* __restrict__ x, const float* __restrict__ y, const float* __restrict__ cvec,
    const float* __restrict__ Wih1, const float* __restrict__ Whh1,
    const float* __restrict__ bih1, const float* __restrict__ bhh1,
    const float* __restrict__ Wih2, const float* __restrict__ Whh2,
    const float* __restrict__ bih2, const float* __restrict__ bhh2,
    const float* __restrict__ Wk, const float* __restrict__ bk,
    const float* __restrict__ Wo, const float* __restrict__ bo,
    float* __restrict__ out, float* __restrict__ ws)
{
  extern __shared__ char dsm[];
  const int blk = blockIdx.x, tid = threadIdx.x;
  const int wv = tid >> 6, l = tid & 63;
  const int q = l & 3;

  f16* AB = (f16*)ws;
  float* outg  = ws + OUTG_OFF;        // [2 parity][64][128]
  float* lossg = ws + LOSS_OFF;
  unsigned* flags = (unsigned*)ws + FLAG_OFF;
  const f16* __restrict__ w2pA = (const f16*)(ws + W2OFF_F);
  const f16* __restrict__ w1pA = (const f16*)(ws + W1OFF_F);
  const f16* __restrict__ wppA = (const f16*)(ws + WPOFF_F);

  f32x4 acc[4];
  float cst[16];
  float bi0 = 0.f, bpr = 0.f, lreg = 0.f;
  #pragma unroll
  for (int z = 0; z < 16; ++z) cst[z] = 0.f;

  // ---------------- role init (no weight loads; only LDS zero + biases) ----
  if (blk < NG1) {                                  // gates1
    int n = wv*16 + (l & 15);
    int R = (n & 3)*512 + blk*32 + (n >> 2);
    bi0 = bih1[R] + bhh1[R];
    unsigned* z = (unsigned*)dsm;
    for (int e = tid; e < 64*G1LW/2; e += NT) z[e] = 0u;
  } else if (blk < G2B + NG2) {                     // gates2
    const int g2i = blk - G2B;
    int n = wv*16 + (l & 15);
    int R = (n & 3)*512 + g2i*32 + (n >> 2);
    bi0 = bih2[R] + bhh2[R];
    unsigned* z = (unsigned*)dsm;
    for (int e = tid; e < 64*G2LW/2; e += NT) z[e] = 0u;
  } else if (blk == PRB) {                          // projection
    int o = wv*16 + (l & 15);
    bpr = (o < 121) ? bo[o] : 0.f;
    unsigned* z = (unsigned*)dsm;
    for (int e = tid; e < 64*PRLW/2; e += NT) z[e] = 0u;
  } else {                                          // attention+loss: batch b
    const int b = blk - ATB;
    f16*   wk  = (f16*)dsm;                         // [30][520]
    float* cv  = (float*)(dsm + 31200);
    float* xl  = (float*)(dsm + 45024);
    float* yl  = (float*)(dsm + 52224);
    for (int e = tid; e < 30*512; e += NT) { int j = e >> 9, k = e & 511; wk[j*520 + k] = (f16)Wk[e]; }
    for (int e = tid; e < 3456; e += NT) cv[e] = cvec[b*3456 + e];
    for (int e = tid; e < 1800; e += NT) { xl[e] = x[b*1800+e]; yl[e] = y[b*1800+e]; }
    float* kap = (float*)(dsm + 61152);
    if (tid < 10) kap[tid] = 0.f;
    __syncthreads();
    if (tid == 0) {   // stage xA(0) into parity-0
      HU h0, h1u, h2u;
      h0.h = (f16)xl[0]; h1u.h = (f16)xl[1]; h2u.h = (f16)xl[2];
      cst32((unsigned*)AB + (b*1088 >> 1),       (unsigned)h0.u | ((unsigned)h1u.u << 16));
      cst32((unsigned*)AB + ((b*1088 + 2) >> 1), (unsigned)h2u.u);
    }
  }

  gbar(flags, 1);

  // ---------------- main recurrence ----------------
  for (int i = 0; i <= 601; ++i) {
    const f16* __restrict__ Acur = AB + (i & 1)*ABEH;
    f16* __restrict__ Anxt = AB + ((i & 1)^1)*ABEH;
    unsigned* AnxtW = (unsigned*)Anxt;

    // ============ Phase A: LSTM gates (panel h-cols in LDS, weights streamed) ============
    if (blk < NG1) {
      if (i <= 599) {                               // gates1 -> h1(i)
        const f16* __restrict__ wp = w1pA + blk*G1PER;
        f16* plds = (f16*)dsm;
        f16* htr  = (f16*)(dsm + 66560);
        #pragma unroll
        for (int z = 0; z < 4; ++z) acc[z] = (f32x4){0,0,0,0};
        const int kb = (l >> 4)*8;
        f16x8 a01[4][2];
        #pragma unroll
        for (int mt = 0; mt < 4; ++mt)
          #pragma unroll
          for (int jd = 0; jd < 2; ++jd)
            a01[mt][jd] = cld16(Acur + ((l&15) + 16*mt)*1088 + jd*32 + kb);
        #pragma unroll 4
        for (int j = 2; j < 18; ++j) {
          f16x8 bfr = *(const f16x8*)(wp + ((j*8 + wv)*64 + l)*8);
          #pragma unroll
          for (int mt = 0; mt < 4; ++mt) {
            f16x8 af = *(const f16x8*)&plds[((l&15) + 16*mt)*G1LW + (j*32 - 64) + kb];
            acc[mt] = __builtin_amdgcn_mfma_f32_16x16x32_f16(af, bfr, acc[mt], 0,0,0);
          }
        }
        VMWAIT();
        #pragma unroll
        for (int jd = 0; jd < 2; ++jd) {
          f16x8 bfr = *(const f16x8*)(wp + ((jd*8 + wv)*64 + l)*8);
          #pragma unroll
          for (int mt = 0; mt < 4; ++mt)
            acc[mt] = __builtin_amdgcn_mfma_f32_16x16x32_f16(a01[mt][jd], bfr, acc[mt], 0,0,0);
        }
        {
          int dloc = wv*4 + ((l & 15) >> 2);
          #pragma unroll
          for (int mt = 0; mt < 4; ++mt)
            #pragma unroll
            for (int r = 0; r < 4; ++r) {
              float xme = acc[mt][r] + bi0;
              float a1 = __shfl_xor(xme, 1), a2 = __shfl_xor(xme, 2), a3 = __shfl_xor(a1, 2);
              float gi = q==0?xme: q==1?a1 : q==2?a2 : a3;
              float gf = q==0?a1 : q==1?xme: q==2?a3 : a2;
              float gg = q==0?a2 : q==1?a3 : q==2?xme: a1;
              float go = q==0?a3 : q==1?a2 : q==2?a1 : xme;
              float c = cst[mt*4 + r];
              c = sigm(gf)*c + sigm(gi)*tanhf(gg);
              cst[mt*4 + r] = c;
              float h = sigm(go)*tanhf(c);
              if (q == 0) htr[(mt*16 + (l>>4)*4 + r)*32 + dloc] = (f16)h;
            }
        }
        __syncthreads();
        if (tid < 256) {
          int m = tid >> 2, qq = tid & 3;
          f16x8 hv = *(const f16x8*)&htr[m*32 + qq*8];
          cst128h(Anxt + m*1088 + 64 + blk*32 + qq*8, hv);
        }
      }
    } else if (blk < G2B + NG2) {
      if (i >= 1 && i <= 600) {                     // gates2 -> h2(i-1)
        const int g2i = blk - G2B;
        const f16* __restrict__ wp = w2pA + g2i*G2PER;
        f16* plds = (f16*)dsm;
        f16* htr  = (f16*)(dsm + 132096);
        #pragma unroll
        for (int z = 0; z < 4; ++z) acc[z] = (f32x4){0,0,0,0};
        const int kb = (l >> 4)*8;
        f16x8 a01[4][2];
        #pragma unroll
        for (int mt = 0; mt < 4; ++mt)
          #pragma unroll
          for (int jd = 0; jd < 2; ++jd)
            a01[mt][jd] = cld16(Acur + ((l&15) + 16*mt)*1088 + jd*32 + kb);
        #pragma unroll 4
        for (int j = 2; j < 34; ++j) {
          f16x8 bfr = *(const f16x8*)(wp + ((j*8 + wv)*64 + l)*8);
          #pragma unroll
          for (int mt = 0; mt < 4; ++mt) {
            f16x8 af = *(const f16x8*)&plds[((l&15) + 16*mt)*G2LW + (j*32 - 64) + kb];
            acc[mt] = __builtin_amdgcn_mfma_f32_16x16x32_f16(af, bfr, acc[mt], 0,0,0);
          }
        }
        VMWAIT();
        #pragma unroll
        for (int jd = 0; jd < 2; ++jd) {
          f16x8 bfr = *(const f16x8*)(wp + ((jd*8 + wv)*64 + l)*8);
          #pragma unroll
          for (int mt = 0; mt < 4; ++mt)
            acc[mt] = __builtin_amdgcn_mfma_f32_16x16x32_f16(a01[mt][jd], bfr, acc[mt], 0,0,0);
        }
        {
          int dloc = wv*4 + ((l & 15) >> 2);
          #pragma unroll
          for (int mt = 0; mt < 4; ++mt)
            #pragma unroll
            for (int r = 0; r < 4; ++r) {
              float xme = acc[mt][r] + bi0;
              float a1 = __shfl_xor(xme, 1), a2 = __shfl_xor(xme, 2), a3 = __shfl_xor(a1, 2);
              float gi = q==0?xme: q==1?a1 : q==2?a2 : a3;
              float gf = q==0?a1 : q==1?xme: q==2?a3 : a2;
              float gg = q==0?a2 : q==1?a3 : q==2?xme: a1;
              float go = q==0?a3 : q==1?a2 : q==2?a1 : xme;
              float c = cst[mt*4 + r];
              c = sigm(gf)*c + sigm(gi)*tanhf(gg);
              cst[mt*4 + r] = c;
              float h = sigm(go)*tanhf(c);
              if (q == 0) htr[(mt*16 + (l>>4)*4 + r)*32 + dloc] = (f16)h;
            }
        }
        __syncthreads();
        if (tid < 256) {
          int m = tid >> 2, qq = tid & 3;
          f16x8 hv = *(const f16x8*)&htr[m*32 + qq*8];
          cst128h(Anxt + m*1088 + 576 + g2i*32 + qq*8, hv);
        }
      }
    }
    gbar(flags, 2 + 2*i);

    // ============ Phase B: attention + proj + loss + panel ingest ============
    if (blk < NG1) {
      if (i <= 599) {                               // ingest h1 cols for next iter
        f16* plds = (f16*)dsm;
        f16x8 tb[8];
        #pragma unroll
        for (int it = 0; it < 8; ++it) {
          int flat = tid + it*512;
          tb[it] = cld16(Anxt + (flat >> 6)*1088 + 64 + (flat & 63)*8);
        }
        VMWAIT();
        #pragma unroll
        for (int it = 0; it < 8; ++it) {
          int flat = tid + it*512;
          *(f16x8*)&plds[(flat >> 6)*G1LW + (flat & 63)*8] = tb[it];
        }
      }
    } else if (blk < G2B + NG2) {
      if (i <= 599) {                               // ingest h1+h2 cols
        f16* plds = (f16*)dsm;
        f16x8 tb[8];
        #pragma unroll
        for (int half = 0; half < 2; ++half) {
          #pragma unroll
          for (int it = 0; it < 8; ++it) {
            int flat = tid + (half*8 + it)*512;
            tb[it] = cld16(Anxt + (flat >> 7)*1088 + 64 + (flat & 127)*8);
          }
          VMWAIT();
          #pragma unroll
          for (int it = 0; it < 8; ++it) {
            int flat = tid + (half*8 + it)*512;
            *(f16x8*)&plds[(flat >> 7)*G2LW + (flat & 127)*8] = tb[it];
          }
        }
      }
    } else if (blk == PRB) {
      if (i >= 1 && i <= 600) {                     // proj: h2(i-1) -> outg parity (i+1)&1
        f16* plds = (f16*)dsm;
        float* otr = (float*)(dsm + 66560);         // [64][128] f32
        float* outp = outg + ((i + 1) & 1)*8192;
        f16x8 tb[8];
        #pragma unroll
        for (int it = 0; it < 8; ++it) {
          int flat = tid + it*512;
          tb[it] = cld16(Anxt + (flat >> 6)*1088 + 576 + (flat & 63)*8);
        }
        VMWAIT();
        #pragma unroll
        for (int it = 0; it < 8; ++it) {
          int flat = tid + it*512;
          *(f16x8*)&plds[(flat >> 6)*PRLW + (flat & 63)*8] = tb[it];
        }
        __syncthreads();
        #pragma unroll
        for (int z = 0; z < 4; ++z) acc[z] = (f32x4){0,0,0,0};
        const int kb = (l >> 4)*8;
        #pragma unroll 4
        for (int j = 0; j < 16; ++j) {
          f16x8 bfr = *(const f16x8*)(wppA + ((j*8 + wv)*64 + l)*8);
          #pragma unroll
          for (int mt = 0; mt < 4; ++mt) {
            f16x8 af = *(const f16x8*)&plds[((l&15) + 16*mt)*PRLW + j*32 + kb];
            acc[mt] = __builtin_amdgcn_mfma_f32_16x16x32_f16(af, bfr, acc[mt], 0,0,0);
          }
        }
        { int o = wv*16 + (l & 15);
          #pragma unroll
          for (int mt = 0; mt < 4; ++mt)
            #pragma unroll
            for (int r = 0; r < 4; ++r)
              otr[(mt*16 + (l>>4)*4 + r)*128 + o] = acc[mt][r] + bpr;
        }
        __syncthreads();
        #pragma unroll
        for (int it = 0; it < 4; ++it) {
          int flat = tid + it*512;
          int m = flat >> 5, o4 = flat & 31;
          f32x4 v4 = *(const f32x4*)&otr[m*128 + o4*4];
          cst128f(outp + m*128 + o4*4, v4);
        }
      }
    } else {
      const int b = blk - ATB;
      f16*   wk   = (f16*)dsm;
      float* cv   = (float*)(dsm + 31200);
      float* xl   = (float*)(dsm + 45024);
      float* yl   = (float*)(dsm + 52224);
      f16*   h1h  = (f16*)(dsm + 59424);
      float* so   = (float*)(dsm + 60448);
      float* skg  = (float*)(dsm + 60944);
      float* sal  = (float*)(dsm + 61072);
      float* sbe  = (float*)(dsm + 61112);
      float* kap  = (float*)(dsm + 61152);
      float* sphi = (float*)(dsm + 61192);
      float* wtmp = (float*)(dsm + 61448);
      if (i <= 599) {                               // attention(i): h1(i) -> w(i)
        if (tid < 64) {
          f16x8 hv = cld16(Anxt + b*1088 + 64 + tid*8);
          VMWAIT();
          *(f16x8*)&h1h[tid*8] = hv;
        }
        __syncthreads();
        {
          int j = tid >> 4, ksv = tid & 15;
          float a = 0.f;
          if (j < 30) {
            const f16* wr = &wk[j*520 + ksv*32];
            const f16* hr = &h1h[ksv*32];
            #pragma unroll
            for (int c = 0; c < 4; ++c) {
              f16x8 qv = *(const f16x8*)(wr + c*8);
              f16x8 hv = *(const f16x8*)(hr + c*8);
              #pragma unroll
              for (int e = 0; e < 8; ++e) a += (float)qv[e] * (float)hv[e];
            }
          }
          a += __shfl_xor(a, 1); a += __shfl_xor(a, 2);
          a += __shfl_xor(a, 4); a += __shfl_xor(a, 8);
          if (j < 30 && ksv == 0) skg[j] = a + bk[j];
        }
        __syncthreads();
        if (tid < 10) {
          sal[tid] = expf(skg[tid]);
          sbe[tid] = expf(skg[10+tid]);
          kap[tid] += expf(skg[20+tid]);
        }
        __syncthreads();
        if (tid < 64) {
          float u = (float)tid, ph = 0.f;
          #pragma unroll
          for (int k2 = 0; k2 < 10; ++k2) {
            float d = kap[k2] - u;
            ph += sal[k2]*expf(-sbe[k2]*d*d);
          }
          sphi[tid] = ph;
        }
        __syncthreads();
        if (tid < 54) {
          float wvv = 0.f;
          #pragma unroll 8
          for (int u = 0; u < 64; ++u) wvv += sphi[u]*cv[u*54 + tid];
          wtmp[tid] = wvv;
        }
        __syncthreads();
        if (tid < 27) {
          HU a, bu; a.h = (f16)wtmp[2*tid]; bu.h = (f16)wtmp[2*tid+1];
          cst32(AnxtW + ((b*1088 + 4 + 2*tid) >> 1), (unsigned)a.u | ((unsigned)bu.u << 16));
        } else if (tid == 27) {
          HU a, bu; a.h = (f16)xl[i*3+0]; bu.h = (f16)xl[i*3+1];
          cst32(AnxtW + ((b*1088 + 58) >> 1), (unsigned)a.u | ((unsigned)bu.u << 16));
        } else if (tid == 28) {
          HU a; a.h = (f16)xl[i*3+2];
          cst32(AnxtW + ((b*1088 + 60) >> 1), (unsigned)a.u);
        } else if (tid == 29 && i <= 598) {
          HU a, bu; a.h = (f16)xl[(i+1)*3+0]; bu.h = (f16)xl[(i+1)*3+1];
          cst32(AnxtW + ((b*1088) >> 1), (unsigned)a.u | ((unsigned)bu.u << 16));
        } else if (tid == 30 && i <= 598) {
          HU a; a.h = (f16)xl[(i+1)*3+2];
          cst32(AnxtW + ((b*1088 + 2) >> 1), (unsigned)a.u);
        }
      }
      if (i >= 2) {                                 // loss(i-2) from outg parity i&1
        if (tid < 121) {
          unsigned uu = ald32((unsigned*)(outg + (i & 1)*8192) + b*128 + tid);
          float v; __builtin_memcpy(&v, &uu, 4);
          so[tid] = v;
        }
        __syncthreads();
        if (tid < 32) {
          float v = mix_loss(so, yl, i-2, tid);
          if (tid == 0) lreg += v;
        }
      }
    }
    gbar(flags, 3 + 2*i);
  }

  if (blk >= ATB && tid == 0) {
    unsigned uu; __builtin_memcpy(&uu, &lreg, 4);
    cst32((unsigned*)lossg + (blk - ATB), uu);
  }
  gbar(flags, 1206);
  if (blk == ATB && tid < 64) {
    unsigned uu = ald32((unsigned*)lossg + tid);
    float v; __builtin_memcpy(&v, &uu, 4);
    #pragma unroll
    for (int d = 32; d >= 1; d >>= 1) v += __shfl_xor(v, d);
    if (tid == 0) out[0] = v / 38400.f;
  }
}

extern "C" void kernel_launch(void* const* d_in, const int* in_sizes, int n_in,
                              void* d_out, int out_size, void* d_ws, size_t ws_size,
                              hipStream_t stream)
{
  (void)in_sizes; (void)n_in; (void)out_size; (void)ws_size;
  const float* x    = (const float*)d_in[0];
  const float* y    = (const float*)d_in[1];
  const float* cvec = (const float*)d_in[2];
  const float* Wih1 = (const float*)d_in[3];
  const float* Whh1 = (const float*)d_in[4];
  const float* bih1 = (const float*)d_in[5];
  const float* bhh1 = (const float*)d_in[6];
  const float* Wih2 = (const float*)d_in[7];
  const float* Whh2 = (const float*)d_in[8];
  const float* bih2 = (const float*)d_in[9];
  const float* bhh2 = (const float*)d_in[10];
  const float* Wk   = (const float*)d_in[11];
  const float* bk   = (const float*)d_in[12];
  const float* Wo   = (const float*)d_in[13];
  const float* bo   = (const float*)d_in[14];
  float* out = (float*)d_out;
  float* wsf = (float*)d_ws;

  hipFuncSetAttribute((const void*)kmain, hipFuncAttributeMaxDynamicSharedMemorySize, DYN_LDS);

  k_init<<<256, 256, 0, stream>>>(wsf, Wih1, Whh1, Wih2, Whh2, Wo);

  void* args[] = {
    (void*)&x, (void*)&y, (void*)&cvec,
    (void*)&Wih1, (void*)&Whh1, (void*)&bih1, (void*)&bhh1,
    (void*)&Wih2, (void*)&Whh2, (void*)&bih2, (void*)&bhh2,
    (void*)&Wk, (void*)&bk, (void*)&Wo, (void*)&bo,
    (void*)&out, (void*)&wsf
  };
  hipLaunchCooperativeKernel((void*)kmain, dim3(NBLK), dim3(NT), args, DYN_LDS, stream);
}

// Round 11
// 12803.107 us; speedup vs baseline: 1.5607x; 1.2089x over previous
//
#include <hip/hip_runtime.h>
#include <math.h>

typedef _Float16 f16;
typedef _Float16 f16x8 __attribute__((ext_vector_type(8)));
typedef float f32x4 __attribute__((ext_vector_type(4)));
union HU { f16 h; unsigned short u; };

#define NT 512
#define NG1 16              // blocks 0..15: gates1, 32 dims each
#define G2B 16
#define NG2 16              // blocks 16..31: gates2, 32 dims each
#define PRB 32
#define ATB 33
#define NBLK 97
#define ABE 69632           // dwords: both panel parity buffers
#define ABEH 69632          // f16 per parity buffer (64 x 1088)
#define OUTG_OFF 69632      // float offset (2 parity buffers of 64x128)
#define LOSS_OFF 86016
#define FLAG_OFF 86144      // [0..97] barrier flags, [128..191] wflags
// prepacked fragment-linear weights (f16), float offsets:
#define W2OFF_F 86400
#define W1OFF_F 1200512
#define WPOFF_F 1790336
#define G2PER 139264
#define G1PER 73728
#define DYN_LDS 136704
#define G1LW 520
#define G2LW 1032
#define PRLW 520

// ---- coherent loads: inline asm sc0 sc1 (bypass L1/L2 -> L3). SAFE only at
// low register pressure (no spills); every path here stays <= ~130 VGPR.
__device__ __forceinline__ f16x8 cld16(const void* p) {
  f16x8 r;
  asm volatile("global_load_dwordx4 %0, %1, off sc0 sc1" : "=v"(r) : "v"(p) : "memory");
  return r;
}
// low-rate loads: compiler-visible atomics (correct even if spilled)
__device__ __forceinline__ unsigned long long ald64(const void* p) {
  return __hip_atomic_load((const unsigned long long*)p, __ATOMIC_RELAXED, __HIP_MEMORY_SCOPE_AGENT);
}
__device__ __forceinline__ unsigned ald32(const void* p) {
  return __hip_atomic_load((const unsigned*)p, __ATOMIC_RELAXED, __HIP_MEMORY_SCOPE_AGENT);
}
// stores: asm (no output reg -> no spill hazard)
__device__ __forceinline__ void cst32(void* p, unsigned v) {
  asm volatile("global_store_dword %0, %1, off sc0 sc1" :: "v"(p), "v"(v) : "memory");
}
__device__ __forceinline__ void cst128h(void* p, f16x8 v) {
  asm volatile("global_store_dwordx4 %0, %1, off sc0 sc1" :: "v"(p), "v"(v) : "memory");
}
__device__ __forceinline__ void cst128f(void* p, f32x4 v) {
  asm volatile("global_store_dwordx4 %0, %1, off sc0 sc1" :: "v"(p), "v"(v) : "memory");
}
#define VMWAIT() do { asm volatile("s_waitcnt vmcnt(0)" ::: "memory"); \
                      __builtin_amdgcn_sched_barrier(0); } while (0)

__device__ __forceinline__ float sigm(float v){ return 1.f/(1.f+expf(-v)); }

// grid barrier: store own flag, poll 49 qwords (flags 0..97)
__device__ __forceinline__ void gbar(unsigned* flags, unsigned target) {
  VMWAIT();
  __syncthreads();
  if (threadIdx.x == 0) cst32(flags + blockIdx.x, target);
  if (threadIdx.x < 64) {
    bool ok;
    do {
      unsigned lo = target, hi = target;
      if (threadIdx.x < 49) {
        unsigned long long v = ald64(flags + threadIdx.x * 2);
        lo = (unsigned)v; hi = (unsigned)(v >> 32);
      }
      ok = (lo >= target) && (hi >= target);
    } while (!__all(ok));
  }
  __syncthreads();
}

// per-wave spin on the 64 w-flags (attention -> gates handoff)
__device__ __forceinline__ void wspin(const unsigned* wflags, unsigned target) {
  int lane = threadIdx.x & 63;
  bool ok;
  do {
    unsigned lo = target, hi = target;
    if (lane < 32) {
      unsigned long long v = ald64(wflags + lane * 2);
      lo = (unsigned)v; hi = (unsigned)(v >> 32);
    }
    ok = (lo >= target) && (hi >= target);
  } while (!__all(ok));
}

__device__ __forceinline__ float mix_loss(const float* so, const float* yl, int t, int m) {
  float y1 = yl[t*3+0], y2 = yl[t*3+1], ys = yl[t*3+2];
  float ph = (m < 20) ? so[1+m] : -1e30f;
  float mx = ph;
  #pragma unroll
  for (int d = 16; d >= 1; d >>= 1) mx = fmaxf(mx, __shfl_xor(mx, d));
  float pe = (m < 20) ? expf(ph - mx) : 0.f;
  float ps = pe;
  #pragma unroll
  for (int d = 16; d >= 1; d >>= 1) ps += __shfl_xor(ps, d);
  float contrib = 0.f;
  if (m < 20) {
    float mu1 = so[21+m], mu2 = so[41+m];
    float s1 = expf(so[61+m]), s2 = expf(so[81+m]);
    float rh = tanhf(so[101+m]);
    float d1 = (y1-mu1)/s1, d2 = (y2-mu2)/s2;
    float omr = 1.f - rh*rh;
    float z = d1*d1 + d2*d2 - 2.f*rh*d1*d2;
    float ga = expf(-z/(2.f*omr)) / (6.283185307179586f * s1 * s2 * sqrtf(omr));
    contrib = (pe/ps)*ga;
  }
  float gs = contrib;
  #pragma unroll
  for (int d = 16; d >= 1; d >>= 1) gs += __shfl_xor(gs, d);
  float lg = -logf(gs + 1e-20f);
  float e = 1.f/(1.f + expf(so[0]));
  float lb = -logf((e + 1e-20f)*ys + (1.f - e + 1e-20f)*(1.f - ys));
  return lg + lb;
}

__global__ __launch_bounds__(256) void k_init(float* ws,
    const float* __restrict__ Wih1, const float* __restrict__ Whh1,
    const float* __restrict__ Wih2, const float* __restrict__ Whh2,
    const float* __restrict__ Wo)
{
  unsigned* w0 = (unsigned*)ws;
  unsigned* fl = (unsigned*)ws + FLAG_OFF;
  int idx = blockIdx.x*256 + threadIdx.x;
  int str = gridDim.x*256;
  for (int e = idx; e < ABE; e += str) w0[e] = 0u;                    // panels
  for (int e = idx; e < 2*8192 + 64; e += str) w0[OUTG_OFF + e] = 0u; // outg+lossg
  if (idx < 256) fl[idx] = (idx < NBLK) ? 0u : (idx < 128 ? 0x7fffffffu : 0u);

  // ---- prepack weights into MFMA-fragment-linear order ----
  f16* w2p = (f16*)(ws + W2OFF_F);
  f16* w1p = (f16*)(ws + W1OFF_F);
  f16* wpp = (f16*)(ws + WPOFF_F);
  const int G2T = 16*G2PER, G1T = 16*G1PER, PPT = 65536;
  for (int e = idx; e < G2T; e += str) {
    int bi = e / G2PER, r0 = e - bi*G2PER;
    int sub = r0 & 7, frag = r0 >> 3;
    int l = frag & 63, t = frag >> 6;
    int nt = t & 7, j = t >> 3;
    int n = nt*16 + (l & 15);
    int R = (n & 3)*512 + bi*32 + (n >> 2);
    int k = j*32 + ((l >> 4) << 3) + sub;
    float v = 0.f;
    if (k >= 4 && k < 58)        v = Wih2[R*569 + 515 + (k-4)];
    else if (k >= 58 && k < 61)  v = Wih2[R*569 + (k-58)];
    else if (k >= 64 && k < 576) v = Wih2[R*569 + 3 + (k-64)];
    else if (k >= 576)           v = Whh2[R*512 + (k-576)];
    w2p[e] = (f16)v;
  }
  for (int e = idx; e < G1T; e += str) {
    int bi = e / G1PER, r0 = e - bi*G1PER;
    int sub = r0 & 7, frag = r0 >> 3;
    int l = frag & 63, t = frag >> 6;
    int nt = t & 7, j = t >> 3;
    int n = nt*16 + (l & 15);
    int R = (n & 3)*512 + bi*32 + (n >> 2);
    int k = j*32 + ((l >> 4) << 3) + sub;
    float v = 0.f;
    if (k < 3)                   v = Wih1[R*57 + k];
    else if (k >= 4 && k < 58)   v = Wih1[R*57 + 3 + (k-4)];
    else if (k >= 64 && k < 576) v = Whh1[R*512 + (k-64)];
    w1p[e] = (f16)v;
  }
  for (int e = idx; e < PPT; e += str) {
    int sub = e & 7, frag = e >> 3;
    int l = frag & 63, t = frag >> 6;
    int nt = t & 7, j = t >> 3;
    int o = nt*16 + (l & 15);
    int k = j*32 + ((l >> 4) << 3) + sub;
    wpp[e] = (o < 121) ? (f16)Wo[o*512 + k] : (f16)0.f;
  }
}

__global__ __launch_bounds__(NT, 1) void kmain(
    const float* __restrict__ x, const float* __restrict__ y, const float* __restrict__ cvec,
    const float* __restrict__ Wih1, const float* __restrict__ Whh1,
    const float* __restrict__ bih1, const float* __restrict__ bhh1,
    const float* __restrict__ Wih2, const float* __restrict__ Whh2,
    const float* __restrict__ bih2, const float* __restrict__ bhh2,
    const float* __restrict__ Wk, const float* __restrict__ bk,
    const float* __restrict__ Wo, const float* __restrict__ bo,
    float* __restrict__ out, float* __restrict__ ws)
{
  extern __shared__ char dsm[];
  const int blk = blockIdx.x, tid = threadIdx.x;
  const int wv = tid >> 6, l = tid & 63;
  const int q = l & 3;

  f16* AB = (f16*)ws;
  float* outg  = ws + OUTG_OFF;        // [2 parity][64][128]
  float* lossg = ws + LOSS_OFF;
  unsigned* flags  = (unsigned*)ws + FLAG_OFF;
  unsigned* wflags = flags + 128;
  const f16* __restrict__ w2pA = (const f16*)(ws + W2OFF_F);
  const f16* __restrict__ w1pA = (const f16*)(ws + W1OFF_F);
  const f16* __restrict__ wppA = (const f16*)(ws + WPOFF_F);

  f32x4 acc[4];
  float cst[16];
  float bi0 = 0.f, bpr = 0.f, lreg = 0.f;
  #pragma unroll
  for (int z = 0; z < 16; ++z) cst[z] = 0.f;

  // ---------------- role init ----------------
  if (blk < NG1) {
    int n = wv*16 + (l & 15);
    int R = (n & 3)*512 + blk*32 + (n >> 2);
    bi0 = bih1[R] + bhh1[R];
  } else if (blk < G2B + NG2) {
    const int g2i = blk - G2B;
    int n = wv*16 + (l & 15);
    int R = (n & 3)*512 + g2i*32 + (n >> 2);
    bi0 = bih2[R] + bhh2[R];
  } else if (blk == PRB) {
    int o = wv*16 + (l & 15);
    bpr = (o < 121) ? bo[o] : 0.f;
  } else {
    const int b = blk - ATB;
    f16*   wk  = (f16*)dsm;                         // [30][520]
    float* cv  = (float*)(dsm + 31200);
    float* xl  = (float*)(dsm + 45024);
    float* yl  = (float*)(dsm + 52224);
    for (int e = tid; e < 30*512; e += NT) { int j = e >> 9, k = e & 511; wk[j*520 + k] = (f16)Wk[e]; }
    for (int e = tid; e < 3456; e += NT) cv[e] = cvec[b*3456 + e];
    for (int e = tid; e < 1800; e += NT) { xl[e] = x[b*1800+e]; yl[e] = y[b*1800+e]; }
    float* kap = (float*)(dsm + 61152);
    if (tid < 10) kap[tid] = 0.f;
    __syncthreads();
    if (tid == 0) {   // stage x(0) into parity-0 cols 0..2
      HU h0, h1u, h2u;
      h0.h = (f16)xl[0]; h1u.h = (f16)xl[1]; h2u.h = (f16)xl[2];
      cst32((unsigned*)AB + (b*1088 >> 1),       (unsigned)h0.u | ((unsigned)h1u.u << 16));
      cst32((unsigned*)AB + ((b*1088 + 2) >> 1), (unsigned)h2u.u);
    }
  }

  gbar(flags, 1);

  // ---------------- main recurrence: ticks 0..602, ONE barrier each ----------------
  for (int t = 0; t <= 602; ++t) {
    const f16* __restrict__ Acur = AB + (t & 1)*ABEH;
    f16* __restrict__ Anxt = AB + ((t & 1)^1)*ABEH;
    unsigned* AcurW = (unsigned*)Acur;

    if (blk < NG1) {
      if (t <= 599) {                               // gates1 -> h1(t)
        const f16* __restrict__ wp = w1pA + blk*G1PER;
        f16* plds = (f16*)dsm;
        f16* htr  = (f16*)(dsm + 66560);
        // ingest h1(t-1) cols 64..575 (barrier-protected)
        {
          f16x8 tb[8];
          #pragma unroll
          for (int it = 0; it < 8; ++it) {
            int flat = tid + it*512;
            tb[it] = cld16(Acur + (flat >> 6)*1088 + 64 + (flat & 63)*8);
          }
          VMWAIT();
          #pragma unroll
          for (int it = 0; it < 8; ++it) {
            int flat = tid + it*512;
            *(f16x8*)&plds[(flat >> 6)*G1LW + (flat & 63)*8] = tb[it];
          }
        }
        __syncthreads();
        #pragma unroll
        for (int z = 0; z < 4; ++z) acc[z] = (f32x4){0,0,0,0};
        const int kb = (l >> 4)*8;
        #pragma unroll 8
        for (int j = 2; j < 18; ++j) {
          f16x8 bfr = *(const f16x8*)(wp + ((j*8 + wv)*64 + l)*8);
          #pragma unroll
          for (int mt = 0; mt < 4; ++mt) {
            f16x8 af = *(const f16x8*)&plds[((l&15) + 16*mt)*G1LW + (j*32 - 64) + kb];
            acc[mt] = __builtin_amdgcn_mfma_f32_16x16x32_f16(af, bfr, acc[mt], 0,0,0);
          }
        }
        // w(t-1)/x(t) handoff: spin, then read cols 0..63
        wspin(wflags, (unsigned)t);
        {
          f16x8 a01[4][2];
          #pragma unroll
          for (int mt = 0; mt < 4; ++mt)
            #pragma unroll
            for (int jd = 0; jd < 2; ++jd)
              a01[mt][jd] = cld16(Acur + ((l&15) + 16*mt)*1088 + jd*32 + kb);
          VMWAIT();
          #pragma unroll
          for (int jd = 0; jd < 2; ++jd) {
            f16x8 bfr = *(const f16x8*)(wp + ((jd*8 + wv)*64 + l)*8);
            #pragma unroll
            for (int mt = 0; mt < 4; ++mt)
              acc[mt] = __builtin_amdgcn_mfma_f32_16x16x32_f16(a01[mt][jd], bfr, acc[mt], 0,0,0);
          }
        }
        {
          int dloc = wv*4 + ((l & 15) >> 2);
          #pragma unroll
          for (int mt = 0; mt < 4; ++mt)
            #pragma unroll
            for (int r = 0; r < 4; ++r) {
              float xme = acc[mt][r] + bi0;
              float a1 = __shfl_xor(xme, 1), a2 = __shfl_xor(xme, 2), a3 = __shfl_xor(a1, 2);
              float gi = q==0?xme: q==1?a1 : q==2?a2 : a3;
              float gf = q==0?a1 : q==1?xme: q==2?a3 : a2;
              float gg = q==0?a2 : q==1?a3 : q==2?xme: a1;
              float go = q==0?a3 : q==1?a2 : q==2?a1 : xme;
              float c = cst[mt*4 + r];
              c = sigm(gf)*c + sigm(gi)*tanhf(gg);
              cst[mt*4 + r] = c;
              float h = sigm(go)*tanhf(c);
              if (q == 0) htr[(mt*16 + (l>>4)*4 + r)*32 + dloc] = (f16)h;
            }
        }
        __syncthreads();
        if (tid < 256) {
          int m = tid >> 2, qq = tid & 3;
          f16x8 hv = *(const f16x8*)&htr[m*32 + qq*8];
          cst128h(Anxt + m*1088 + 64 + blk*32 + qq*8, hv);
        }
      }
    } else if (blk < G2B + NG2) {
      if (t >= 1 && t <= 600) {                     // gates2 -> h2(t-1)
        const int g2i = blk - G2B;
        const f16* __restrict__ wp = w2pA + g2i*G2PER;
        f16* plds = (f16*)dsm;
        f16* htr  = (f16*)(dsm + 132096);
        // ingest h1(t-1)+h2(t-2) cols 64..1087, one VMWAIT
        {
          f16x8 tb[16];
          #pragma unroll
          for (int it = 0; it < 16; ++it) {
            int flat = tid + it*512;
            tb[it] = cld16(Acur + (flat >> 7)*1088 + 64 + (flat & 127)*8);
          }
          VMWAIT();
          #pragma unroll
          for (int it = 0; it < 16; ++it) {
            int flat = tid + it*512;
            *(f16x8*)&plds[(flat >> 7)*G2LW + (flat & 127)*8] = tb[it];
          }
        }
        __syncthreads();
        #pragma unroll
        for (int z = 0; z < 4; ++z) acc[z] = (f32x4){0,0,0,0};
        const int kb = (l >> 4)*8;
        #pragma unroll 8
        for (int j = 2; j < 34; ++j) {
          f16x8 bfr = *(const f16x8*)(wp + ((j*8 + wv)*64 + l)*8);
          #pragma unroll
          for (int mt = 0; mt < 4; ++mt) {
            f16x8 af = *(const f16x8*)&plds[((l&15) + 16*mt)*G2LW + (j*32 - 64) + kb];
            acc[mt] = __builtin_amdgcn_mfma_f32_16x16x32_f16(af, bfr, acc[mt], 0,0,0);
          }
        }
        wspin(wflags, (unsigned)t);
        {
          f16x8 a01[4][2];
          #pragma unroll
          for (int mt = 0; mt < 4; ++mt)
            #pragma unroll
            for (int jd = 0; jd < 2; ++jd)
              a01[mt][jd] = cld16(Acur + ((l&15) + 16*mt)*1088 + jd*32 + kb);
          VMWAIT();
          #pragma unroll
          for (int jd = 0; jd < 2; ++jd) {
            f16x8 bfr = *(const f16x8*)(wp + ((jd*8 + wv)*64 + l)*8);
            #pragma unroll
            for (int mt = 0; mt < 4; ++mt)
              acc[mt] = __builtin_amdgcn_mfma_f32_16x16x32_f16(a01[mt][jd], bfr, acc[mt], 0,0,0);
          }
        }
        {
          int dloc = wv*4 + ((l & 15) >> 2);
          #pragma unroll
          for (int mt = 0; mt < 4; ++mt)
            #pragma unroll
            for (int r = 0; r < 4; ++r) {
              float xme = acc[mt][r] + bi0;
              float a1 = __shfl_xor(xme, 1), a2 = __shfl_xor(xme, 2), a3 = __shfl_xor(a1, 2);
              float gi = q==0?xme: q==1?a1 : q==2?a2 : a3;
              float gf = q==0?a1 : q==1?xme: q==2?a3 : a2;
              float gg = q==0?a2 : q==1?a3 : q==2?xme: a1;
              float go = q==0?a3 : q==1?a2 : q==2?a1 : xme;
              float c = cst[mt*4 + r];
              c = sigm(gf)*c + sigm(gi)*tanhf(gg);
              cst[mt*4 + r] = c;
              float h = sigm(go)*tanhf(c);
              if (q == 0) htr[(mt*16 + (l>>4)*4 + r)*32 + dloc] = (f16)h;
            }
        }
        __syncthreads();
        if (tid < 256) {
          int m = tid >> 2, qq = tid & 3;
          f16x8 hv = *(const f16x8*)&htr[m*32 + qq*8];
          cst128h(Anxt + m*1088 + 576 + g2i*32 + qq*8, hv);
        }
      }
    } else if (blk == PRB) {
      if (t >= 2 && t <= 601) {                     // proj: outputs(t-2) -> outg[t&1]
        f16* plds = (f16*)dsm;
        float* otr = (float*)(dsm + 66560);
        float* outp = outg + (t & 1)*8192;
        {
          f16x8 tb[8];
          #pragma unroll
          for (int it = 0; it < 8; ++it) {
            int flat = tid + it*512;
            tb[it] = cld16(Acur + (flat >> 6)*1088 + 576 + (flat & 63)*8);
          }
          VMWAIT();
          #pragma unroll
          for (int it = 0; it < 8; ++it) {
            int flat = tid + it*512;
            *(f16x8*)&plds[(flat >> 6)*PRLW + (flat & 63)*8] = tb[it];
          }
        }
        __syncthreads();
        #pragma unroll
        for (int z = 0; z < 4; ++z) acc[z] = (f32x4){0,0,0,0};
        const int kb = (l >> 4)*8;
        #pragma unroll 8
        for (int j = 0; j < 16; ++j) {
          f16x8 bfr = *(const f16x8*)(wppA + ((j*8 + wv)*64 + l)*8);
          #pragma unroll
          for (int mt = 0; mt < 4; ++mt) {
            f16x8 af = *(const f16x8*)&plds[((l&15) + 16*mt)*PRLW + j*32 + kb];
            acc[mt] = __builtin_amdgcn_mfma_f32_16x16x32_f16(af, bfr, acc[mt], 0,0,0);
          }
        }
        { int o = wv*16 + (l & 15);
          #pragma unroll
          for (int mt = 0; mt < 4; ++mt)
            #pragma unroll
            for (int r = 0; r < 4; ++r)
              otr[(mt*16 + (l>>4)*4 + r)*128 + o] = acc[mt][r] + bpr;
        }
        __syncthreads();
        #pragma unroll
        for (int it = 0; it < 4; ++it) {
          int flat = tid + it*512;
          int m = flat >> 5, o4 = flat & 31;
          f32x4 v4 = *(const f32x4*)&otr[m*128 + o4*4];
          cst128f(outp + m*128 + o4*4, v4);
        }
      }
    } else {
      const int b = blk - ATB;
      f16*   wk   = (f16*)dsm;
      float* cv   = (float*)(dsm + 31200);
      float* xl   = (float*)(dsm + 45024);
      float* yl   = (float*)(dsm + 52224);
      f16*   h1h  = (f16*)(dsm + 59424);
      float* so   = (float*)(dsm + 60448);
      float* skg  = (float*)(dsm + 60944);
      float* sal  = (float*)(dsm + 61072);
      float* sbe  = (float*)(dsm + 61112);
      float* kap  = (float*)(dsm + 61152);
      float* sphi = (float*)(dsm + 61192);
      float* wtmp = (float*)(dsm + 61448);
      if (t >= 1 && t <= 600) {                     // attention step s=t-1: h1(s) -> w(s)
        const int s = t - 1;
        if (tid < 64) {
          f16x8 hv = cld16(Acur + b*1088 + 64 + tid*8);
          VMWAIT();
          *(f16x8*)&h1h[tid*8] = hv;
        }
        __syncthreads();
        {
          int j = tid >> 4, ksv = tid & 15;
          float a = 0.f;
          if (j < 30) {
            const f16* wr = &wk[j*520 + ksv*32];
            const f16* hr = &h1h[ksv*32];
            #pragma unroll
            for (int c = 0; c < 4; ++c) {
              f16x8 qv = *(const f16x8*)(wr + c*8);
              f16x8 hv = *(const f16x8*)(hr + c*8);
              #pragma unroll
              for (int e = 0; e < 8; ++e) a += (float)qv[e] * (float)hv[e];
            }
          }
          a += __shfl_xor(a, 1); a += __shfl_xor(a, 2);
          a += __shfl_xor(a, 4); a += __shfl_xor(a, 8);
          if (j < 30 && ksv == 0) skg[j] = a + bk[j];
        }
        __syncthreads();
        if (tid < 10) {
          sal[tid] = expf(skg[tid]);
          sbe[tid] = expf(skg[10+tid]);
          kap[tid] += expf(skg[20+tid]);
        }
        __syncthreads();
        if (tid < 64) {
          float u = (float)tid, ph = 0.f;
          #pragma unroll
          for (int k2 = 0; k2 < 10; ++k2) {
            float d = kap[k2] - u;
            ph += sal[k2]*expf(-sbe[k2]*d*d);
          }
          sphi[tid] = ph;
        }
        __syncthreads();
        if (tid < 54) {
          float wvv = 0.f;
          #pragma unroll 8
          for (int u = 0; u < 64; ++u) wvv += sphi[u]*cv[u*54 + tid];
          wtmp[tid] = wvv;
        }
        __syncthreads();
        // write w(s)@4..57, x(s)@58..60, x(s+1)@0..2 into Acur (cols 0..63)
        if (tid < 27) {
          HU a, bu; a.h = (f16)wtmp[2*tid]; bu.h = (f16)wtmp[2*tid+1];
          cst32(AcurW + ((b*1088 + 4 + 2*tid) >> 1), (unsigned)a.u | ((unsigned)bu.u << 16));
        } else if (tid == 27) {
          HU a, bu; a.h = (f16)xl[s*3+0]; bu.h = (f16)xl[s*3+1];
          cst32(AcurW + ((b*1088 + 58) >> 1), (unsigned)a.u | ((unsigned)bu.u << 16));
        } else if (tid == 28) {
          HU a; a.h = (f16)xl[s*3+2];
          cst32(AcurW + ((b*1088 + 60) >> 1), (unsigned)a.u);
        } else if (tid == 29 && s <= 598) {
          HU a, bu; a.h = (f16)xl[(s+1)*3+0]; bu.h = (f16)xl[(s+1)*3+1];
          cst32(AcurW + ((b*1088) >> 1), (unsigned)a.u | ((unsigned)bu.u << 16));
        } else if (tid == 30 && s <= 598) {
          HU a; a.h = (f16)xl[(s+1)*3+2];
          cst32(AcurW + ((b*1088 + 2) >> 1), (unsigned)a.u);
        }
        VMWAIT();
        __syncthreads();
        if (tid == 0) cst32(wflags + b, (unsigned)t);
      }
      if (t >= 3) {                                 // loss step t-3 from outg[(t&1)^1]
        if (tid < 121) {
          unsigned uu = ald32((unsigned*)(outg + ((t & 1)^1)*8192) + b*128 + tid);
          float v; __builtin_memcpy(&v, &uu, 4);
          so[tid] = v;
        }
        __syncthreads();
        if (tid < 32) {
          float v = mix_loss(so, yl, t-3, tid);
          if (tid == 0) lreg += v;
        }
      }
    }
    gbar(flags, 2 + t);
  }

  if (blk >= ATB && tid == 0) {
    unsigned uu; __builtin_memcpy(&uu, &lreg, 4);
    cst32((unsigned*)lossg + (blk - ATB), uu);
  }
  gbar(flags, 606);
  if (blk == ATB && tid < 64) {
    unsigned uu = ald32((unsigned*)lossg + tid);
    float v; __builtin_memcpy(&v, &uu, 4);
    #pragma unroll
    for (int d = 32; d >= 1; d >>= 1) v += __shfl_xor(v, d);
    if (tid == 0) out[0] = v / 38400.f;
  }
}

extern "C" void kernel_launch(void* const* d_in, const int* in_sizes, int n_in,
                              void* d_out, int out_size, void* d_ws, size_t ws_size,
                              hipStream_t stream)
{
  (void)in_sizes; (void)n_in; (void)out_size; (void)ws_size;
  const float* x    = (const float*)d_in[0];
  const float* y    = (const float*)d_in[1];
  const float* cvec = (const float*)d_in[2];
  const float* Wih1 = (const float*)d_in[3];
  const float* Whh1 = (const float*)d_in[4];
  const float* bih1 = (const float*)d_in[5];
  const float* bhh1 = (const float*)d_in[6];
  const float* Wih2 = (const float*)d_in[7];
  const float* Whh2 = (const float*)d_in[8];
  const float* bih2 = (const float*)d_in[9];
  const float* bhh2 = (const float*)d_in[10];
  const float* Wk   = (const float*)d_in[11];
  const float* bk   = (const float*)d_in[12];
  const float* Wo   = (const float*)d_in[13];
  const float* bo   = (const float*)d_in[14];
  float* out = (float*)d_out;
  float* wsf = (float*)d_ws;

  hipFuncSetAttribute((const void*)kmain, hipFuncAttributeMaxDynamicSharedMemorySize, DYN_LDS);

  k_init<<<256, 256, 0, stream>>>(wsf, Wih1, Whh1, Wih2, Whh2, Wo);

  void* args[] = {
    (void*)&x, (void*)&y, (void*)&cvec,
    (void*)&Wih1, (void*)&Whh1, (void*)&bih1, (void*)&bhh1,
    (void*)&Wih2, (void*)&Whh2, (void*)&bih2, (void*)&bhh2,
    (void*)&Wk, (void*)&bk, (void*)&Wo, (void*)&bo,
    (void*)&out, (void*)&wsf
  };
  hipLaunchCooperativeKernel((void*)kmain, dim3(NBLK), dim3(NT), args, DYN_LDS, stream);
}

// Round 12
// 11274.369 us; speedup vs baseline: 1.7723x; 1.1356x over previous
//
#include <hip/hip_runtime.h>
#include <math.h>

typedef _Float16 f16;
typedef _Float16 f16x8 __attribute__((ext_vector_type(8)));
typedef float f32x4 __attribute__((ext_vector_type(4)));
union HU { f16 h; unsigned short u; };

#define NT 512
#define NG1 16              // blocks 0..15: gates1, 32 dims each
#define G2B 16
#define NG2 16              // blocks 16..31: gates2, 32 dims each
#define PRB 32
#define ATB 33
#define NBLK 97
#define ABE 69632           // dwords: both panel parity buffers
#define ABEH 69632          // f16 per parity buffer (64 x 1088)
#define OUTG_OFF 69632      // float offset (2 parity buffers of 64x128)
#define LOSS_OFF 86016
#define FLAG_OFF 86144      // barrier flags: 97 x 16-dword lines
#define HFLG_OFF 87744      // h1 flags: 16 x 16-dword lines (uint offset)
// prepacked fragment-linear weights (f16), float offsets:
#define W2OFF_F 88064
#define W1OFF_F 1202176
#define WPOFF_F 1792000
#define G2PER 139264
#define G1PER 73728
#define DYN_LDS 136704
#define G1LW 584            // g1 panel LDS row: 576 + 8 pad
#define G2LW 1032
#define PRLW 520

// ---- coherent loads: inline asm sc0 sc1 (bypass L1/L2). SAFE only at low
// register pressure (no spills); every path here stays <= ~130 VGPR.
__device__ __forceinline__ f16x8 cld16(const void* p) {
  f16x8 r;
  asm volatile("global_load_dwordx4 %0, %1, off sc0 sc1" : "=v"(r) : "v"(p) : "memory");
  return r;
}
// low-rate loads: compiler-visible atomics (correct even if spilled)
__device__ __forceinline__ unsigned ald32(const void* p) {
  return __hip_atomic_load((const unsigned*)p, __ATOMIC_RELAXED, __HIP_MEMORY_SCOPE_AGENT);
}
// stores: asm (no output reg -> no spill hazard)
__device__ __forceinline__ void cst32(void* p, unsigned v) {
  asm volatile("global_store_dword %0, %1, off sc0 sc1" :: "v"(p), "v"(v) : "memory");
}
__device__ __forceinline__ void cst128h(void* p, f16x8 v) {
  asm volatile("global_store_dwordx4 %0, %1, off sc0 sc1" :: "v"(p), "v"(v) : "memory");
}
__device__ __forceinline__ void cst128f(void* p, f32x4 v) {
  asm volatile("global_store_dwordx4 %0, %1, off sc0 sc1" :: "v"(p), "v"(v) : "memory");
}
#define VMWAIT() do { asm volatile("s_waitcnt vmcnt(0)" ::: "memory"); \
                      __builtin_amdgcn_sched_barrier(0); } while (0)

__device__ __forceinline__ float sigm(float v){ return 1.f/(1.f+expf(-v)); }

// grid barrier: padded flag lines (no cacheline contention), poll 97 lines
__device__ __forceinline__ void gbar(unsigned* flags, unsigned target) {
  VMWAIT();
  __syncthreads();
  if (threadIdx.x == 0) cst32(flags + blockIdx.x * 16, target);
  if (threadIdx.x < 64) {
    int lane = threadIdx.x;
    bool ok;
    do {
      unsigned v0 = ald32(flags + lane * 16);
      unsigned v1 = (lane < 33) ? ald32(flags + (64 + lane) * 16) : target;
      ok = (v0 >= target) && (v1 >= target);
    } while (!__all(ok));
  }
  __syncthreads();
}

__device__ __forceinline__ float mix_loss(const float* so, const float* yl, int t, int m) {
  float y1 = yl[t*3+0], y2 = yl[t*3+1], ys = yl[t*3+2];
  float ph = (m < 20) ? so[1+m] : -1e30f;
  float mx = ph;
  #pragma unroll
  for (int d = 16; d >= 1; d >>= 1) mx = fmaxf(mx, __shfl_xor(mx, d));
  float pe = (m < 20) ? expf(ph - mx) : 0.f;
  float ps = pe;
  #pragma unroll
  for (int d = 16; d >= 1; d >>= 1) ps += __shfl_xor(ps, d);
  float contrib = 0.f;
  if (m < 20) {
    float mu1 = so[21+m], mu2 = so[41+m];
    float s1 = expf(so[61+m]), s2 = expf(so[81+m]);
    float rh = tanhf(so[101+m]);
    float d1 = (y1-mu1)/s1, d2 = (y2-mu2)/s2;
    float omr = 1.f - rh*rh;
    float z = d1*d1 + d2*d2 - 2.f*rh*d1*d2;
    float ga = expf(-z/(2.f*omr)) / (6.283185307179586f * s1 * s2 * sqrtf(omr));
    contrib = (pe/ps)*ga;
  }
  float gs = contrib;
  #pragma unroll
  for (int d = 16; d >= 1; d >>= 1) gs += __shfl_xor(gs, d);
  float lg = -logf(gs + 1e-20f);
  float e = 1.f/(1.f + expf(so[0]));
  float lb = -logf((e + 1e-20f)*ys + (1.f - e + 1e-20f)*(1.f - ys));
  return lg + lb;
}

__global__ __launch_bounds__(256) void k_init(float* ws,
    const float* __restrict__ Wih1, const float* __restrict__ Whh1,
    const float* __restrict__ Wih2, const float* __restrict__ Whh2,
    const float* __restrict__ Wo)
{
  unsigned* w0 = (unsigned*)ws;
  int idx = blockIdx.x*256 + threadIdx.x;
  int str = gridDim.x*256;
  for (int e = idx; e < ABE; e += str) w0[e] = 0u;                    // panels
  for (int e = idx; e < 2*8192 + 64; e += str) w0[OUTG_OFF + e] = 0u; // outg+lossg
  for (int e = idx; e < HFLG_OFF + 256 - FLAG_OFF; e += str) w0[FLAG_OFF + e] = 0u; // flags

  f16* w2p = (f16*)(ws + W2OFF_F);
  f16* w1p = (f16*)(ws + W1OFF_F);
  f16* wpp = (f16*)(ws + WPOFF_F);
  const int G2T = 16*G2PER, G1T = 16*G1PER, PPT = 65536;
  for (int e = idx; e < G2T; e += str) {
    int bi = e / G2PER, r0 = e - bi*G2PER;
    int sub = r0 & 7, frag = r0 >> 3;
    int l = frag & 63, t = frag >> 6;
    int nt = t & 7, j = t >> 3;
    int n = nt*16 + (l & 15);
    int R = (n & 3)*512 + bi*32 + (n >> 2);
    int k = j*32 + ((l >> 4) << 3) + sub;
    float v = 0.f;
    if (k >= 4 && k < 58)        v = Wih2[R*569 + 515 + (k-4)];
    else if (k >= 58 && k < 61)  v = Wih2[R*569 + (k-58)];
    else if (k >= 64 && k < 576) v = Wih2[R*569 + 3 + (k-64)];
    else if (k >= 576)           v = Whh2[R*512 + (k-576)];
    w2p[e] = (f16)v;
  }
  for (int e = idx; e < G1T; e += str) {
    int bi = e / G1PER, r0 = e - bi*G1PER;
    int sub = r0 & 7, frag = r0 >> 3;
    int l = frag & 63, t = frag >> 6;
    int nt = t & 7, j = t >> 3;
    int n = nt*16 + (l & 15);
    int R = (n & 3)*512 + bi*32 + (n >> 2);
    int k = j*32 + ((l >> 4) << 3) + sub;
    float v = 0.f;
    if (k < 3)                   v = Wih1[R*57 + k];
    else if (k >= 4 && k < 58)   v = Wih1[R*57 + 3 + (k-4)];
    else if (k >= 64 && k < 576) v = Whh1[R*512 + (k-64)];
    w1p[e] = (f16)v;
  }
  for (int e = idx; e < PPT; e += str) {
    int sub = e & 7, frag = e >> 3;
    int l = frag & 63, t = frag >> 6;
    int nt = t & 7, j = t >> 3;
    int o = nt*16 + (l & 15);
    int k = j*32 + ((l >> 4) << 3) + sub;
    wpp[e] = (o < 121) ? (f16)Wo[o*512 + k] : (f16)0.f;
  }
}

__global__ __launch_bounds__(NT, 1) void kmain(
    const float* __restrict__ x, const float* __restrict__ y, const float* __restrict__ cvec,
    const float* __restrict__ Wih1, const float* __restrict__ Whh1,
    const float* __restrict__ bih1, const float* __restrict__ bhh1,
    const float* __restrict__ Wih2, const float* __restrict__ Whh2,
    const float* __restrict__ bih2, const float* __restrict__ bhh2,
    const float* __restrict__ Wk, const float* __restrict__ bk,
    const float* __restrict__ Wo, const float* __restrict__ bo,
    float* __restrict__ out, float* __restrict__ ws)
{
  extern __shared__ char dsm[];
  const int blk = blockIdx.x, tid = threadIdx.x;
  const int wv = tid >> 6, l = tid & 63;
  const int q = l & 3;

  f16* AB = (f16*)ws;
  float* outg  = ws + OUTG_OFF;        // [2 parity][64][128]
  float* lossg = ws + LOSS_OFF;
  unsigned* flags  = (unsigned*)ws + FLAG_OFF;
  unsigned* hflags = (unsigned*)ws + HFLG_OFF;
  const f16* __restrict__ w2pA = (const f16*)(ws + W2OFF_F);
  const f16* __restrict__ w1pA = (const f16*)(ws + W1OFF_F);
  const f16* __restrict__ wppA = (const f16*)(ws + WPOFF_F);

  f32x4 acc[4];
  float cst[16];
  float bi0 = 0.f, bpr = 0.f, lreg = 0.f;
  #pragma unroll
  for (int z = 0; z < 16; ++z) cst[z] = 0.f;

  // ---------------- role init ----------------
  if (blk < NG1) {
    int n = wv*16 + (l & 15);
    int R = (n & 3)*512 + blk*32 + (n >> 2);
    bi0 = bih1[R] + bhh1[R];
  } else if (blk < G2B + NG2) {
    const int g2i = blk - G2B;
    int n = wv*16 + (l & 15);
    int R = (n & 3)*512 + g2i*32 + (n >> 2);
    bi0 = bih2[R] + bhh2[R];
  } else if (blk == PRB) {
    int o = wv*16 + (l & 15);
    bpr = (o < 121) ? bo[o] : 0.f;
  } else {
    const int b = blk - ATB;
    f16*   wk  = (f16*)dsm;                         // [30][520]
    float* cv  = (float*)(dsm + 31200);
    float* xl  = (float*)(dsm + 45024);
    float* yl  = (float*)(dsm + 52224);
    for (int e = tid; e < 30*512; e += NT) { int j = e >> 9, k = e & 511; wk[j*520 + k] = (f16)Wk[e]; }
    for (int e = tid; e < 3456; e += NT) cv[e] = cvec[b*3456 + e];
    for (int e = tid; e < 1800; e += NT) { xl[e] = x[b*1800+e]; yl[e] = y[b*1800+e]; }
    float* kap = (float*)(dsm + 61152);
    if (tid < 10) kap[tid] = 0.f;
    __syncthreads();
    if (tid == 0) {   // stage x(0) into parity-0 cols 0..2
      HU h0, h1u, h2u;
      h0.h = (f16)xl[0]; h1u.h = (f16)xl[1]; h2u.h = (f16)xl[2];
      cst32((unsigned*)AB + (b*1088 >> 1),       (unsigned)h0.u | ((unsigned)h1u.u << 16));
      cst32((unsigned*)AB + ((b*1088 + 2) >> 1), (unsigned)h2u.u);
    }
  }

  gbar(flags, 1);

  // ---------------- main recurrence: ticks 0..602, one barrier each ----------------
  for (int t = 0; t <= 602; ++t) {
    const f16* __restrict__ Acur = AB + (t & 1)*ABEH;
    f16* __restrict__ Anxt = AB + ((t & 1)^1)*ABEH;
    unsigned* AnxtW = (unsigned*)Anxt;

    if (blk < NG1) {
      if (t <= 599) {                               // gates1 -> h1(t); w already in Acur
        const f16* __restrict__ wp = w1pA + blk*G1PER;
        f16* plds = (f16*)dsm;                      // [64][G1LW]
        f16* htr  = (f16*)(dsm + 74752);
        // single contiguous ingest: cols 0..575 (w,x | h1), 9 loads, one VMWAIT
        {
          f16x8 tb[9];
          #pragma unroll
          for (int it = 0; it < 9; ++it) {
            int flat = it*512 + tid;
            int row = flat / 72, c8 = flat - row*72;
            tb[it] = cld16(Acur + row*1088 + c8*8);
          }
          VMWAIT();
          #pragma unroll
          for (int it = 0; it < 9; ++it) {
            int flat = it*512 + tid;
            int row = flat / 72, c8 = flat - row*72;
            *(f16x8*)&plds[row*G1LW + c8*8] = tb[it];
          }
        }
        __syncthreads();
        #pragma unroll
        for (int z = 0; z < 4; ++z) acc[z] = (f32x4){0,0,0,0};
        const int kb = (l >> 4)*8;
        #pragma unroll 6
        for (int j = 0; j < 18; ++j) {
          f16x8 bfr = *(const f16x8*)(wp + ((j*8 + wv)*64 + l)*8);
          #pragma unroll
          for (int mt = 0; mt < 4; ++mt) {
            f16x8 af = *(const f16x8*)&plds[((l&15) + 16*mt)*G1LW + j*32 + kb];
            acc[mt] = __builtin_amdgcn_mfma_f32_16x16x32_f16(af, bfr, acc[mt], 0,0,0);
          }
        }
        {
          int dloc = wv*4 + ((l & 15) >> 2);
          #pragma unroll
          for (int mt = 0; mt < 4; ++mt)
            #pragma unroll
            for (int r = 0; r < 4; ++r) {
              float xme = acc[mt][r] + bi0;
              float a1 = __shfl_xor(xme, 1), a2 = __shfl_xor(xme, 2), a3 = __shfl_xor(a1, 2);
              float gi = q==0?xme: q==1?a1 : q==2?a2 : a3;
              float gf = q==0?a1 : q==1?xme: q==2?a3 : a2;
              float gg = q==0?a2 : q==1?a3 : q==2?xme: a1;
              float go = q==0?a3 : q==1?a2 : q==2?a1 : xme;
              float c = cst[mt*4 + r];
              c = sigm(gf)*c + sigm(gi)*tanhf(gg);
              cst[mt*4 + r] = c;
              float h = sigm(go)*tanhf(c);
              if (q == 0) htr[(mt*16 + (l>>4)*4 + r)*32 + dloc] = (f16)h;
            }
        }
        __syncthreads();
        if (tid < 256) {
          int m = tid >> 2, qq = tid & 3;
          f16x8 hv = *(const f16x8*)&htr[m*32 + qq*8];
          cst128h(Anxt + m*1088 + 64 + blk*32 + qq*8, hv);
        }
        // publish h1(t): drain all waves' stores, then set padded flag
        VMWAIT();
        __syncthreads();
        if (tid == 0) cst32(hflags + blk*16, (unsigned)(t + 1));
      }
    } else if (blk < G2B + NG2) {
      if (t >= 1 && t <= 600) {                     // gates2 -> h2(t-1)
        const int g2i = blk - G2B;
        const f16* __restrict__ wp = w2pA + g2i*G2PER;
        f16* plds = (f16*)dsm;
        f16* htr  = (f16*)(dsm + 132096);
        {
          f16x8 tb[16];
          #pragma unroll
          for (int it = 0; it < 16; ++it) {
            int flat = tid + it*512;
            tb[it] = cld16(Acur + (flat >> 7)*1088 + 64 + (flat & 127)*8);
          }
          VMWAIT();
          #pragma unroll
          for (int it = 0; it < 16; ++it) {
            int flat = tid + it*512;
            *(f16x8*)&plds[(flat >> 7)*G2LW + (flat & 127)*8] = tb[it];
          }
        }
        __syncthreads();
        #pragma unroll
        for (int z = 0; z < 4; ++z) acc[z] = (f32x4){0,0,0,0};
        const int kb = (l >> 4)*8;
        #pragma unroll 8
        for (int j = 2; j < 34; ++j) {
          f16x8 bfr = *(const f16x8*)(wp + ((j*8 + wv)*64 + l)*8);
          #pragma unroll
          for (int mt = 0; mt < 4; ++mt) {
            f16x8 af = *(const f16x8*)&plds[((l&15) + 16*mt)*G2LW + (j*32 - 64) + kb];
            acc[mt] = __builtin_amdgcn_mfma_f32_16x16x32_f16(af, bfr, acc[mt], 0,0,0);
          }
        }
        // w/x part (cols 0..63), barrier-protected in Acur — no spin needed
        {
          f16x8 a01[4][2];
          #pragma unroll
          for (int mt = 0; mt < 4; ++mt)
            #pragma unroll
            for (int jd = 0; jd < 2; ++jd)
              a01[mt][jd] = cld16(Acur + ((l&15) + 16*mt)*1088 + jd*32 + kb);
          VMWAIT();
          #pragma unroll
          for (int jd = 0; jd < 2; ++jd) {
            f16x8 bfr = *(const f16x8*)(wp + ((jd*8 + wv)*64 + l)*8);
            #pragma unroll
            for (int mt = 0; mt < 4; ++mt)
              acc[mt] = __builtin_amdgcn_mfma_f32_16x16x32_f16(a01[mt][jd], bfr, acc[mt], 0,0,0);
          }
        }
        {
          int dloc = wv*4 + ((l & 15) >> 2);
          #pragma unroll
          for (int mt = 0; mt < 4; ++mt)
            #pragma unroll
            for (int r = 0; r < 4; ++r) {
              float xme = acc[mt][r] + bi0;
              float a1 = __shfl_xor(xme, 1), a2 = __shfl_xor(xme, 2), a3 = __shfl_xor(a1, 2);
              float gi = q==0?xme: q==1?a1 : q==2?a2 : a3;
              float gf = q==0?a1 : q==1?xme: q==2?a3 : a2;
              float gg = q==0?a2 : q==1?a3 : q==2?xme: a1;
              float go = q==0?a3 : q==1?a2 : q==2?a1 : xme;
              float c = cst[mt*4 + r];
              c = sigm(gf)*c + sigm(gi)*tanhf(gg);
              cst[mt*4 + r] = c;
              float h = sigm(go)*tanhf(c);
              if (q == 0) htr[(mt*16 + (l>>4)*4 + r)*32 + dloc] = (f16)h;
            }
        }
        __syncthreads();
        if (tid < 256) {
          int m = tid >> 2, qq = tid & 3;
          f16x8 hv = *(const f16x8*)&htr[m*32 + qq*8];
          cst128h(Anxt + m*1088 + 576 + g2i*32 + qq*8, hv);
        }
      }
    } else if (blk == PRB) {
      if (t >= 2 && t <= 601) {                     // proj: outputs(t-2) -> outg[t&1]
        f16* plds = (f16*)dsm;
        float* otr = (float*)(dsm + 66560);
        float* outp = outg + (t & 1)*8192;
        {
          f16x8 tb[8];
          #pragma unroll
          for (int it = 0; it < 8; ++it) {
            int flat = tid + it*512;
            tb[it] = cld16(Acur + (flat >> 6)*1088 + 576 + (flat & 63)*8);
          }
          VMWAIT();
          #pragma unroll
          for (int it = 0; it < 8; ++it) {
            int flat = tid + it*512;
            *(f16x8*)&plds[(flat >> 6)*PRLW + (flat & 63)*8] = tb[it];
          }
        }
        __syncthreads();
        #pragma unroll
        for (int z = 0; z < 4; ++z) acc[z] = (f32x4){0,0,0,0};
        const int kb = (l >> 4)*8;
        #pragma unroll 8
        for (int j = 0; j < 16; ++j) {
          f16x8 bfr = *(const f16x8*)(wppA + ((j*8 + wv)*64 + l)*8);
          #pragma unroll
          for (int mt = 0; mt < 4; ++mt) {
            f16x8 af = *(const f16x8*)&plds[((l&15) + 16*mt)*PRLW + j*32 + kb];
            acc[mt] = __builtin_amdgcn_mfma_f32_16x16x32_f16(af, bfr, acc[mt], 0,0,0);
          }
        }
        { int o = wv*16 + (l & 15);
          #pragma unroll
          for (int mt = 0; mt < 4; ++mt)
            #pragma unroll
            for (int r = 0; r < 4; ++r)
              otr[(mt*16 + (l>>4)*4 + r)*128 + o] = acc[mt][r] + bpr;
        }
        __syncthreads();
        #pragma unroll
        for (int it = 0; it < 4; ++it) {
          int flat = tid + it*512;
          int m = flat >> 5, o4 = flat & 31;
          f32x4 v4 = *(const f32x4*)&otr[m*128 + o4*4];
          cst128f(outp + m*128 + o4*4, v4);
        }
      }
    } else {
      const int b = blk - ATB;
      f16*   wk   = (f16*)dsm;
      float* cv   = (float*)(dsm + 31200);
      float* xl   = (float*)(dsm + 45024);
      float* yl   = (float*)(dsm + 52224);
      f16*   h1h  = (f16*)(dsm + 59424);
      float* so   = (float*)(dsm + 60448);
      float* skg  = (float*)(dsm + 60944);
      float* sal  = (float*)(dsm + 61072);
      float* sbe  = (float*)(dsm + 61112);
      float* kap  = (float*)(dsm + 61152);
      float* sphi = (float*)(dsm + 61192);
      float* wtmp = (float*)(dsm + 61448);
      // loss FIRST (overlaps gates' GEMM window): step t-3 from outg[(t&1)^1]
      if (t >= 3) {
        if (tid < 121) {
          unsigned uu = ald32((unsigned*)(outg + ((t & 1)^1)*8192) + b*128 + tid);
          float v; __builtin_memcpy(&v, &uu, 4);
          so[tid] = v;
        }
        __syncthreads();
        if (tid < 32) {
          float v = mix_loss(so, yl, t-3, tid);
          if (tid == 0) lreg += v;
        }
        __syncthreads();
      }
      if (t <= 599) {                               // attention step s=t: h1(t) -> w(t) into Anxt
        const int s = t;
        // wait for all 16 g1 blocks to publish h1(t)
        if (tid < 64) {
          bool ok;
          do {
            unsigned v = (tid < 16) ? ald32(hflags + tid*16) : (unsigned)(t+1);
            ok = v >= (unsigned)(t+1);
          } while (!__all(ok));
        }
        __syncthreads();
        if (tid < 64) {
          f16x8 hv = cld16(Anxt + b*1088 + 64 + tid*8);
          VMWAIT();
          *(f16x8*)&h1h[tid*8] = hv;
        }
        __syncthreads();
        {
          int j = tid >> 4, ksv = tid & 15;
          float a = 0.f;
          if (j < 30) {
            const f16* wr = &wk[j*520 + ksv*32];
            const f16* hr = &h1h[ksv*32];
            #pragma unroll
            for (int c = 0; c < 4; ++c) {
              f16x8 qv = *(const f16x8*)(wr + c*8);
              f16x8 hv = *(const f16x8*)(hr + c*8);
              #pragma unroll
              for (int e = 0; e < 8; ++e) a += (float)qv[e] * (float)hv[e];
            }
          }
          a += __shfl_xor(a, 1); a += __shfl_xor(a, 2);
          a += __shfl_xor(a, 4); a += __shfl_xor(a, 8);
          if (j < 30 && ksv == 0) skg[j] = a + bk[j];
        }
        __syncthreads();
        if (tid < 10) {
          sal[tid] = expf(skg[tid]);
          sbe[tid] = expf(skg[10+tid]);
          kap[tid] += expf(skg[20+tid]);
        }
        __syncthreads();
        if (tid < 64) {
          float u = (float)tid, ph = 0.f;
          #pragma unroll
          for (int k2 = 0; k2 < 10; ++k2) {
            float d = kap[k2] - u;
            ph += sal[k2]*expf(-sbe[k2]*d*d);
          }
          sphi[tid] = ph;
        }
        __syncthreads();
        if (tid < 54) {
          float wvv = 0.f;
          #pragma unroll 8
          for (int u = 0; u < 64; ++u) wvv += sphi[u]*cv[u*54 + tid];
          wtmp[tid] = wvv;
        }
        __syncthreads();
        // write w(s)@4..57, x(s)@58..60, x(s+1)@0..2 into ANXT (cols 0..63)
        if (tid < 27) {
          HU a, bu; a.h = (f16)wtmp[2*tid]; bu.h = (f16)wtmp[2*tid+1];
          cst32(AnxtW + ((b*1088 + 4 + 2*tid) >> 1), (unsigned)a.u | ((unsigned)bu.u << 16));
        } else if (tid == 27) {
          HU a, bu; a.h = (f16)xl[s*3+0]; bu.h = (f16)xl[s*3+1];
          cst32(AnxtW + ((b*1088 + 58) >> 1), (unsigned)a.u | ((unsigned)bu.u << 16));
        } else if (tid == 28) {
          HU a; a.h = (f16)xl[s*3+2];
          cst32(AnxtW + ((b*1088 + 60) >> 1), (unsigned)a.u);
        } else if (tid == 29 && s <= 598) {
          HU a, bu; a.h = (f16)xl[(s+1)*3+0]; bu.h = (f16)xl[(s+1)*3+1];
          cst32(AnxtW + ((b*1088) >> 1), (unsigned)a.u | ((unsigned)bu.u << 16));
        } else if (tid == 30 && s <= 598) {
          HU a; a.h = (f16)xl[(s+1)*3+2];
          cst32(AnxtW + ((b*1088 + 2) >> 1), (unsigned)a.u);
        }
      }
    }
    gbar(flags, 2 + t);
  }

  if (blk >= ATB && tid == 0) {
    unsigned uu; __builtin_memcpy(&uu, &lreg, 4);
    cst32((unsigned*)lossg + (blk - ATB), uu);
  }
  gbar(flags, 610);
  if (blk == ATB && tid < 64) {
    unsigned uu = ald32((unsigned*)lossg + tid);
    float v; __builtin_memcpy(&v, &uu, 4);
    #pragma unroll
    for (int d = 32; d >= 1; d >>= 1) v += __shfl_xor(v, d);
    if (tid == 0) out[0] = v / 38400.f;
  }
}

extern "C" void kernel_launch(void* const* d_in, const int* in_sizes, int n_in,
                              void* d_out, int out_size, void* d_ws, size_t ws_size,
                              hipStream_t stream)
{
  (void)in_sizes; (void)n_in; (void)out_size; (void)ws_size;
  const float* x    = (const float*)d_in[0];
  const float* y    = (const float*)d_in[1];
  const float* cvec = (const float*)d_in[2];
  const float* Wih1 = (const float*)d_in[3];
  const float* Whh1 = (const float*)d_in[4];
  const float* bih1 = (const float*)d_in[5];
  const float* bhh1 = (const float*)d_in[6];
  const float* Wih2 = (const float*)d_in[7];
  const float* Whh2 = (const float*)d_in[8];
  const float* bih2 = (const float*)d_in[9];
  const float* bhh2 = (const float*)d_in[10];
  const float* Wk   = (const float*)d_in[11];
  const float* bk   = (const float*)d_in[12];
  const float* Wo   = (const float*)d_in[13];
  const float* bo   = (const float*)d_in[14];
  float* out = (float*)d_out;
  float* wsf = (float*)d_ws;

  hipFuncSetAttribute((const void*)kmain, hipFuncAttributeMaxDynamicSharedMemorySize, DYN_LDS);

  k_init<<<256, 256, 0, stream>>>(wsf, Wih1, Whh1, Wih2, Whh2, Wo);

  void* args[] = {
    (void*)&x, (void*)&y, (void*)&cvec,
    (void*)&Wih1, (void*)&Whh1, (void*)&bih1, (void*)&bhh1,
    (void*)&Wih2, (void*)&Whh2, (void*)&bih2, (void*)&bhh2,
    (void*)&Wk, (void*)&bk, (void*)&Wo, (void*)&bo,
    (void*)&out, (void*)&wsf
  };
  hipLaunchCooperativeKernel((void*)kmain, dim3(NBLK), dim3(NT), args, DYN_LDS, stream);
}